// Round 1
// 11796.931 us; speedup vs baseline: 1.0570x; 1.0570x over previous
//
#include <hip/hip_runtime.h>
#include <math.h>
#include <stdint.h>

// ---------------------------------------------------------------------------
// Speller decoder, persistent kernel, 512 blocks x 256 threads.
// R4: single-pass attention. LF chunk is staged through LDS in 8-row tiles
// (coalesced float4 loads, register prefetch one tile ahead); energies AND
// the context weighted-sum are computed from LDS with online-softmax
// rescaling. LF global traffic per step drops 128 MB -> 64 MB and becomes
// perfectly coalesced (was: lane-strided 2KB energy pass + column context
// pass). Everything else (R3 structure) unchanged: relaxed AGENT-scope
// atomics through L3, monotonic counter barriers, LSTM fused in gate GEMM.
// ---------------------------------------------------------------------------

#define NB 512
#define NT 256

constexpr int Tv = 1024, Vv = 5000, STEPS = 64;

// ---- u32 counter region (all monotonic, zeroed by init kernel) ----
constexpr int MCNT = 0;               // master barrier counter
constexpr int GEN  = 16;              // barrier generation
constexpr int GCNT = 64;              // 32 group counters, stride 16
constexpr int GFLG = 1024;            // 32 group release flags, stride 32
constexpr int ACNT = 2048;            // 32 attn-merge counters, stride 16
constexpr int LCNT = 2560;            // 32 logits-merge counters, stride 16
constexpr int WSU  = 4096;

// ---- float region offsets (wsf = (float*)ws + WSU) ----
constexpr int XH   = 0;                    // [32][1024] = emb(512) | ctx(512)
constexpr int HB   = XH + 32*1024;         // [2][32][512] h double-buffer
constexpr int HID  = HB + 2*32*512;        // [32][512]
constexpr int PART = HID + 32*512;         // [32][4][16][130] attn partials
constexpr int E3   = PART + 32*4*16*130;   // [32][1024] head-3 energies
constexpr int PM   = E3 + 32*1024;         // [32][256] chunk max
constexpr int PSUM = PM + 32*256;          // [32][256] chunk sumexp
constexpr int PIDX = PSUM + 32*256;        // [32][256] chunk argmax (int)
constexpr int MLS  = PIDX + 32*256;        // [32][2] (max, lse)

__device__ __forceinline__ float sigm(float x) { return 1.f / (1.f + expf(-x)); }

// ---- coherent (L3, sc0 sc1) access helpers: relaxed agent atomics ----
__device__ __forceinline__ float ld4(const float* p) {
  return __hip_atomic_load(const_cast<float*>(p), __ATOMIC_RELAXED, __HIP_MEMORY_SCOPE_AGENT);
}
__device__ __forceinline__ void st4(float* p, float v) {
  __hip_atomic_store(p, v, __ATOMIC_RELAXED, __HIP_MEMORY_SCOPE_AGENT);
}
__device__ __forceinline__ float2 ld8(const float* p) {
  unsigned long long u = __hip_atomic_load(
      reinterpret_cast<unsigned long long*>(const_cast<float*>(p)),
      __ATOMIC_RELAXED, __HIP_MEMORY_SCOPE_AGENT);
  union { unsigned long long u; float2 f; } c; c.u = u; return c.f;
}
__device__ __forceinline__ void st8(float* p, float2 v) {
  union { float2 f; unsigned long long u; } c; c.f = v;
  __hip_atomic_store(reinterpret_cast<unsigned long long*>(p), c.u,
                     __ATOMIC_RELAXED, __HIP_MEMORY_SCOPE_AGENT);
}
__device__ __forceinline__ int ld4i(const int* p) {
  return (int)__hip_atomic_load(reinterpret_cast<unsigned*>(const_cast<int*>(p)),
                                __ATOMIC_RELAXED, __HIP_MEMORY_SCOPE_AGENT);
}
__device__ __forceinline__ void st4i(int* p, int v) {
  __hip_atomic_store(reinterpret_cast<unsigned*>(p), (unsigned)v,
                     __ATOMIC_RELAXED, __HIP_MEMORY_SCOPE_AGENT);
}
__device__ __forceinline__ unsigned ld_rlx(unsigned* p) {
  return __hip_atomic_load(p, __ATOMIC_RELAXED, __HIP_MEMORY_SCOPE_AGENT);
}
__device__ __forceinline__ void st_rlx(unsigned* p, unsigned v) {
  __hip_atomic_store(p, v, __ATOMIC_RELAXED, __HIP_MEMORY_SCOPE_AGENT);
}
__device__ __forceinline__ unsigned add_rlx(unsigned* p, unsigned v) {
  return __hip_atomic_fetch_add(p, v, __ATOMIC_RELAXED, __HIP_MEMORY_SCOPE_AGENT);
}

// Device barrier: NO cache ops. __syncthreads drains vmcnt (sc1 stores are
// then in L3 = globally visible); counters/flags are relaxed sc1 atomics.
__device__ __forceinline__ void gsync(unsigned* wsu, int blk, int tid, unsigned& myGen) {
  __syncthreads();
  if (tid == 0) {
    const unsigned target = ++myGen;
    const int grp = blk >> 4;
    unsigned o = add_rlx(&wsu[GCNT + grp*16], 1u);
    if (o == target*16u - 1u) {
      unsigned o2 = add_rlx(&wsu[MCNT], 1u);
      if (o2 == target*32u - 1u) st_rlx(&wsu[GEN], target);
    }
    if ((blk & 15) == 0) {
      while (ld_rlx(&wsu[GEN]) != target) __builtin_amdgcn_s_sleep(2);
      st_rlx(&wsu[GFLG + grp*32], target);
    } else {
      while (ld_rlx(&wsu[GFLG + grp*32]) != target) __builtin_amdgcn_s_sleep(2);
    }
  }
  __syncthreads();
}

__global__ void speller_init(const float* __restrict__ LF, const float* __restrict__ Emb,
                             float* __restrict__ wsf, unsigned* __restrict__ wsu) {
  int b = blockIdx.x;
  for (int i = threadIdx.x; i < 512; i += NT) {
    st4(wsf + XH + b*1024 + i,       Emb[i]);                    // emb row 0
    st4(wsf + XH + b*1024 + 512 + i, LF[(size_t)b*Tv*512 + i]);  // ctx0 = LF[b,0,:]
    st4(wsf + HB + b*512 + i,        0.f);                       // h0 (buffer 0)
  }
  if (b == 0) for (int i = threadIdx.x; i < WSU; i += NT) st_rlx(wsu + i, 0u);
}

struct LdsA { float Wg[8][1536]; float gb[8]; };   // gate rows: i,i,f,f,g,g,o,o of units 2j,2j+1
struct LdsB { float Wc[20][512]; float Wp[2][1024]; float bcl[20]; float bpl[2]; };
union  LdsU { LdsA a; LdsB b; };

__launch_bounds__(NT, 2)
__global__ void speller_main(const float* __restrict__ LF, const float* __restrict__ Emb,
                             const float* __restrict__ Wih, const float* __restrict__ Whh,
                             const float* __restrict__ bih, const float* __restrict__ bhh,
                             const float* __restrict__ Wp,  const float* __restrict__ bp,
                             const float* __restrict__ Wc,  const float* __restrict__ bc,
                             float* __restrict__ out, unsigned* __restrict__ wsu,
                             float* __restrict__ wsf) {
  const int blk = blockIdx.x, tid = threadIdx.x;
  unsigned myGen = 0;
  __shared__ LdsU lds;
  __shared__ float scr[784];
  __shared__ int  sint[300];
  // LF tile buffer: 8 rows x 512 floats, rows padded to 516 (spreads banks
  // across the 8-row dimension: 516 % 32 == 4).
  __shared__ float lfl[8 * 516];

  // ---------------- one-time LDS weight preload (plain cached loads) -------
  if (blk < 256) {
    const int u0 = blk * 2;
    for (int idx = tid; idx < 8*1536; idx += NT) {
      int r = idx / 1536, k = idx - r*1536;
      int g = r >> 1, uu = r & 1;
      int row = g*512 + u0 + uu;
      lds.a.Wg[r][k] = (k < 1024) ? Wih[(size_t)row*1024 + k]
                                  : Whh[(size_t)row*512 + (k-1024)];
    }
    if (tid < 8) {
      int g = tid >> 1, uu = tid & 1, row = g*512 + u0 + uu;
      lds.a.gb[tid] = bih[row] + bhh[row];
    }
  } else {
    const int blk2 = blk - 256, v0 = blk2*20, rp0 = blk2*2;
    if (v0 < Vv) {
      for (int idx = tid; idx < 20*512; idx += NT) {
        int vi = idx >> 9, k = idx & 511;
        lds.b.Wc[vi][k] = Wc[(size_t)(v0+vi)*512 + k];
      }
      if (tid < 20) lds.b.bcl[tid] = bc[v0+tid];
    }
    for (int idx = tid; idx < 2048; idx += NT) {
      int r = idx >> 10, k = idx & 1023;
      lds.b.Wp[r][k] = Wp[(size_t)(rp0+r)*1024 + k];
    }
    if (tid < 2) lds.b.bpl[tid] = bp[rp0+tid];
  }
  __syncthreads();

  float c_reg[2][4];                 // cell state, lives in registers all run
#pragma unroll
  for (int uu = 0; uu < 2; ++uu)
#pragma unroll
    for (int i = 0; i < 4; ++i) c_reg[uu][i] = 0.f;
  float lgv[20];                     // logits carried phase4 -> next phase1

#pragma unroll 1
  for (int s = 0; s < STEPS; ++s) {
    const int rbuf = s & 1, wbuf = (s + 1) & 1;

    // ===== Phase 1: gates GEMM + fused LSTM (blk<256) | out-write (>=256) ==
    if (blk < 256) {
      const int u0 = blk * 2;
      const int slot = tid >> 5, ks = tid & 31, b0 = slot * 4;
      float acc[8][4];
#pragma unroll
      for (int r = 0; r < 8; ++r)
#pragma unroll
        for (int i = 0; i < 4; ++i) acc[r][i] = 0.f;
      const float* x1 = wsf + XH;                  // [32][1024] emb|ctx
      const float* x2 = wsf + HB + rbuf*16384;     // [32][512]  h
#pragma unroll 2
      for (int q = 0; q < 8; ++q) {                // k in [0,1024): emb|ctx
        const int kq = q*32 + ks;
        float2 xa[4], xb[4];
#pragma unroll
        for (int i = 0; i < 4; ++i) {
          const float* p = x1 + (size_t)(b0+i)*1024 + kq*4;
          xa[i] = ld8(p); xb[i] = ld8(p + 2);
        }
#pragma unroll
        for (int r = 0; r < 8; ++r) {
          float4 wv = *(const float4*)(&lds.a.Wg[r][kq*4]);
#pragma unroll
          for (int i = 0; i < 4; ++i)
            acc[r][i] += wv.x*xa[i].x + wv.y*xa[i].y + wv.z*xb[i].x + wv.w*xb[i].y;
        }
      }
#pragma unroll 2
      for (int q = 0; q < 4; ++q) {                // k in [1024,1536): h
        const int kq = q*32 + ks;
        float2 xa[4], xb[4];
#pragma unroll
        for (int i = 0; i < 4; ++i) {
          const float* p = x2 + (size_t)(b0+i)*512 + kq*4;
          xa[i] = ld8(p); xb[i] = ld8(p + 2);
        }
#pragma unroll
        for (int r = 0; r < 8; ++r) {
          float4 wv = *(const float4*)(&lds.a.Wg[r][1024 + kq*4]);
#pragma unroll
          for (int i = 0; i < 4; ++i)
            acc[r][i] += wv.x*xa[i].x + wv.y*xa[i].y + wv.z*xb[i].x + wv.w*xb[i].y;
        }
      }
#pragma unroll
      for (int r = 0; r < 8; ++r)
#pragma unroll
        for (int i = 0; i < 4; ++i) {
          float v = acc[r][i];
          v += __shfl_xor(v, 16); v += __shfl_xor(v, 8); v += __shfl_xor(v, 4);
          v += __shfl_xor(v, 2);  v += __shfl_xor(v, 1);
          acc[r][i] = v + lds.a.gb[r];
        }
      // fused LSTM pointwise (rows: i=uu, f=2+uu, g=4+uu, o=6+uu)
      float hnew[2][4];
#pragma unroll
      for (int uu = 0; uu < 2; ++uu)
#pragma unroll
        for (int i = 0; i < 4; ++i) {
          float cn = sigm(acc[2+uu][i]) * c_reg[uu][i]
                   + sigm(acc[uu][i]) * tanhf(acc[4+uu][i]);
          c_reg[uu][i] = cn;
          hnew[uu][i] = sigm(acc[6+uu][i]) * tanhf(cn);
        }
      if (ks == 0) {
#pragma unroll
        for (int i = 0; i < 4; ++i)
          st8(wsf + HB + wbuf*16384 + (size_t)(b0+i)*512 + u0,
              make_float2(hnew[0][i], hnew[1][i]));
      }
    } else if (s > 0) {
      const int blk2 = blk - 256;
      if (blk2 < 250) {
        const int v0 = blk2 * 20, bb = tid >> 3, ks = tid & 7;
        if (ks == 0) {
          float2 ml = ld8(wsf + MLS + 2*bb);
          float sub = ml.x + ml.y;
#pragma unroll
          for (int vi = 0; vi < 20; ++vi)
            out[(size_t)(s-1)*160000 + (size_t)bb*5000 + v0 + vi] = lgv[vi] - sub;
        }
      }
    }
    gsync(wsu, blk, tid, myGen);

    // ============ Phase 2: attention, single-pass LF via LDS tiles ==========
    // Block (b,tc) owns t in [tc*64, tc*64+64). 8 tiles of 8 t-rows each are
    // staged through lfl with one-ahead register prefetch; energies and the
    // online-rescaled context accumulation both read lfl. LF is read ONCE.
    {
      const int b = blk >> 4, tc = blk & 15;
      const int t0 = tc * 64;
      float* hs = scr;  // [512] decoder state
      {
        float2 hv = ld8(wsf + HB + wbuf*16384 + (size_t)b*512 + tid*2);
        hs[tid*2] = hv.x; hs[tid*2+1] = hv.y;
      }
      const int w = tid >> 6, ln = tid & 63;   // wave <-> head
      const int tt = ln >> 3, kk = ln & 7;     // 8 lanes per t-row for energy
      const int rr = tid >> 7, cc = (tid & 127) * 4;   // staging coords
      // running per-head state; lane ln owns context dims w*128+2ln, +1
      float m = -1e30f, l = 0.f, c0 = 0.f, c1 = 0.f;
      const float4* lfg = (const float4*)(LF + ((size_t)(b*Tv + t0))*512);
      float4 pf0 = lfg[tid], pf1 = lfg[256 + tid],
             pf2 = lfg[512 + tid], pf3 = lfg[768 + tid];
#pragma unroll 1
      for (int it = 0; it < 8; ++it) {
        __syncthreads();               // lfl free (prev tile consumed); hs ready
        *(float4*)&lfl[(rr    )*516 + cc] = pf0;
        *(float4*)&lfl[(rr + 2)*516 + cc] = pf1;
        *(float4*)&lfl[(rr + 4)*516 + cc] = pf2;
        *(float4*)&lfl[(rr + 6)*516 + cc] = pf3;
        if (it < 7) {                  // prefetch next tile into registers
          const float4* g2 = lfg + (size_t)(it + 1) * 1024;
          pf0 = g2[tid]; pf1 = g2[256 + tid]; pf2 = g2[512 + tid]; pf3 = g2[768 + tid];
        }
        __syncthreads();               // lfl tile ready
        // ---- energy for t = t0 + it*8 + tt (8 lanes x 16 floats each) ----
        float e = 0.f;
        {
          const float4* lp = (const float4*)&lfl[tt*516 + w*128 + kk*16];
          const float4* hp = (const float4*)&hs[w*128 + kk*16];
#pragma unroll
          for (int q = 0; q < 4; ++q) {
            float4 f = lp[q], hh = hp[q];
            e += f.x*hh.x + f.y*hh.y + f.z*hh.z + f.w*hh.w;
          }
        }
        e += __shfl_xor(e, 1); e += __shfl_xor(e, 2); e += __shfl_xor(e, 4);
        if (w == 3 && kk == 0)
          st4(wsf + E3 + (size_t)b*1024 + t0 + it*8 + tt, e);
        // ---- broadcast the tile's 8 energies to every lane of the wave ----
        float e8[8];
#pragma unroll
        for (int j = 0; j < 8; ++j) e8[j] = __shfl(e, j*8);
        float pm = fmaxf(fmaxf(fmaxf(e8[0],e8[1]), fmaxf(e8[2],e8[3])),
                         fmaxf(fmaxf(e8[4],e8[5]), fmaxf(e8[6],e8[7])));
        float mn = fmaxf(m, pm);
        float rs = expf(m - mn);       // first tile: exp(-huge) == 0
        l *= rs; c0 *= rs; c1 *= rs;
        m = mn;
        const float* crow = &lfl[w*128 + 2*ln];
#pragma unroll
        for (int j = 0; j < 8; ++j) {
          float p = expf(e8[j] - m);
          l += p;
          float2 f = *(const float2*)(crow + j*516);
          c0 += p*f.x; c1 += p*f.y;
        }
      }
      // ---- chunk partials (identical layout to R3) ----
      float* pr = wsf + PART + (size_t)((b*4 + w)*16 + tc)*130;
      st8(pr + 2 + 2*ln, make_float2(c0, c1));
      if (ln == 0) st8(pr, make_float2(m, l));
      __syncthreads();   // drains vmcnt: all this block's partials are in L3
      if (tid == 0) {
        unsigned old = add_rlx(&wsu[ACNT + b*16], 1u);
        sint[0] = (old == (unsigned)(s*16 + 15));
      }
      __syncthreads();
      if (sint[0]) {                       // last arriver merges the 16 chunks
        const int w2 = tid >> 6, ln2 = tid & 63;
        const float* pb = wsf + PART + (size_t)(b*4 + w2)*16*130;
        float M = -1e30f;
        float mv[16], lv[16];
#pragma unroll
        for (int i = 0; i < 16; ++i) { float2 t = ld8(pb + i*130); mv[i] = t.x; lv[i] = t.y; M = fmaxf(M, t.x); }
        float L = 0.f;
        float sc[16];
#pragma unroll
        for (int i = 0; i < 16; ++i) { sc[i] = expf(mv[i] - M); L += lv[i] * sc[i]; }
        float cc0 = 0.f, cc1 = 0.f;
#pragma unroll
        for (int i = 0; i < 16; ++i) {
          float2 cx = ld8(pb + i*130 + 2 + 2*ln2);
          cc0 += sc[i]*cx.x; cc1 += sc[i]*cx.y;
        }
        float invL = 1.f / L;
        st8(wsf + XH + (size_t)b*1024 + 512 + w2*128 + 2*ln2,
            make_float2(cc0*invL, cc1*invL));
        if (ln2 == 0) { scr[768 + w2*2] = M; scr[769 + w2*2] = L; }
        __syncthreads();
        float M3 = scr[768 + 6], iL3 = 1.f / scr[768 + 7];
        for (int i = tid; i < 1024; i += NT)
          out[(size_t)10240000 + ((size_t)(s*32 + b))*1024 + i] =
              expf(ld4(wsf + E3 + (size_t)b*1024 + i) - M3) * iL3;
      }
    }
    gsync(wsu, blk, tid, myGen);

    // ============ Phase 3: MLP hid = relu([h,ctx] @ Wp^T + bp) ===============
    if (blk >= 256) {
      const int blk2 = blk - 256, rp0 = blk2*2;
      const int bb = tid & 31, ks = tid >> 5;        // 8 K-windows of 128
      const float* xr = (ks < 4) ? (wsf + HB + wbuf*16384 + (size_t)bb*512 + ks*128)
                                 : (wsf + XH + (size_t)bb*1024 + (ks-4)*128 + 512);
      const int kb = ks * 128;
      const float4* w0 = (const float4*)(&lds.b.Wp[0][kb]);
      const float4* w1 = (const float4*)(&lds.b.Wp[1][kb]);
      float a0 = 0.f, a1 = 0.f;
#pragma unroll 8
      for (int q = 0; q < 32; ++q) {
        float2 xva = ld8(xr + q*4), xvb = ld8(xr + q*4 + 2);
        float4 wv0 = w0[q], wv1 = w1[q];
        a0 += wv0.x*xva.x + wv0.y*xva.y + wv0.z*xvb.x + wv0.w*xvb.y;
        a1 += wv1.x*xva.x + wv1.y*xva.y + wv1.z*xvb.x + wv1.w*xvb.y;
      }
      scr[ks*32 + bb] = a0; scr[256 + ks*32 + bb] = a1;
      __syncthreads();
      if (tid < 64) {
        int r = tid >> 5, b2 = tid & 31;
        float ssum = 0.f;
#pragma unroll
        for (int j = 0; j < 8; ++j) ssum += scr[r*256 + j*32 + b2];
        ssum += lds.b.bpl[r];
        st4(wsf + HID + (size_t)b2*512 + rp0 + r, fmaxf(ssum, 0.f));
      }
      __syncthreads();
    }
    gsync(wsu, blk, tid, myGen);

    // ============ Phase 4: logits + softmax/argmax partials + merge ==========
    if (blk >= 256) {
      const int blk2 = blk - 256;
      if (blk2 < 250) {
        const int v0 = blk2 * 20;
        const int bb = tid >> 3, ks = tid & 7;       // interleaved K chunks
        float4 xr[16];
        const float* hb = wsf + HID + (size_t)bb*512;
#pragma unroll
        for (int q = 0; q < 16; ++q) {
          const float* p = hb + (q*8 + ks)*4;
          float2 a = ld8(p), b2v = ld8(p + 2);
          xr[q] = make_float4(a.x, a.y, b2v.x, b2v.y);
        }
#pragma unroll
        for (int vi = 0; vi < 20; ++vi) {
          float a = 0.f;
#pragma unroll
          for (int q = 0; q < 16; ++q) {
            float4 wv = *(const float4*)(&lds.b.Wc[vi][(q*8 + ks)*4]);
            a += wv.x*xr[q].x + wv.y*xr[q].y + wv.z*xr[q].z + wv.w*xr[q].w;
          }
          a += __shfl_xor(a, 1); a += __shfl_xor(a, 2); a += __shfl_xor(a, 4);
          lgv[vi] = a + lds.b.bcl[vi];
        }
        float mych = lgv[0]; int ami = 0;
#pragma unroll
        for (int vi = 1; vi < 20; ++vi)
          if (lgv[vi] > mych) { mych = lgv[vi]; ami = vi; }
        float sume = 0.f;
#pragma unroll
        for (int vi = 0; vi < 20; ++vi) sume += expf(lgv[vi] - mych);
        if (ks == 0) {
          st4(wsf + PM + bb*256 + blk2, mych);
          st4(wsf + PSUM + bb*256 + blk2, sume);
          st4i((int*)(wsf + PIDX) + bb*256 + blk2, v0 + ami);
        }
      }
      __syncthreads();   // drain: partials in L3
      if (tid < 32) {
        unsigned old = 0xffffffffu;
        if (blk2 < 250) old = add_rlx(&wsu[LCNT + tid*16], 1u);
        sint[1 + tid] = (old == (unsigned)(s*250 + 249));
      }
      __syncthreads();
      for (int b2 = 0; b2 < 32; ++b2) {
        if (sint[1 + b2]) {                 // last arriver for batch b2 merges
          float mv = -1e30f, sv = 0.f; int iv = 0x7fffffff;
          if (tid < 250) {
            mv = ld4(wsf + PM + b2*256 + tid);
            sv = ld4(wsf + PSUM + b2*256 + tid);
            iv = ld4i((const int*)(wsf + PIDX) + b2*256 + tid);
          }
          scr[tid] = mv; sint[40 + tid] = iv;
          __syncthreads();
          for (int off = 128; off; off >>= 1) {
            if (tid < off) {
              float m2 = scr[tid + off]; int i2 = sint[40 + tid + off];
              if (m2 > scr[tid] || (m2 == scr[tid] && i2 < sint[40 + tid])) {
                scr[tid] = m2; sint[40 + tid] = i2;
              }
            }
            __syncthreads();
          }
          float M = scr[0]; int tok = sint[40];
          __syncthreads();
          scr[tid] = sv * expf(mv - M);
          __syncthreads();
          for (int off = 128; off; off >>= 1) {
            if (tid < off) scr[tid] += scr[tid + off];
            __syncthreads();
          }
          if (tid == 0) st8(wsf + MLS + 2*b2, make_float2(M, logf(scr[0])));
          for (int i = tid; i < 256; i += NT) {
            const float2* er = (const float2*)(Emb + (size_t)tok*512);
            st8(wsf + XH + (size_t)b2*1024 + 2*i, er[i]);
          }
          __syncthreads();
        }
      }
    }
    gsync(wsu, blk, tid, myGen);
  }

  // ---------------- epilogue: step 63's log-softmax from registers ----------
  if (blk >= 256) {
    const int blk2 = blk - 256;
    if (blk2 < 250) {
      const int v0 = blk2 * 20, bb = tid >> 3, ks = tid & 7;
      if (ks == 0) {
        float2 ml = ld8(wsf + MLS + 2*bb);
        float sub = ml.x + ml.y;
#pragma unroll
        for (int vi = 0; vi < 20; ++vi)
          out[(size_t)63*160000 + (size_t)bb*5000 + v0 + vi] = lgv[vi] - sub;
      }
    }
  }
}

extern "C" void kernel_launch(void* const* d_in, const int* in_sizes, int n_in,
                              void* d_out, int out_size, void* d_ws, size_t ws_size,
                              hipStream_t stream) {
  (void)in_sizes; (void)n_in; (void)out_size; (void)ws_size;
  const float* LF  = (const float*)d_in[0];
  const float* Emb = (const float*)d_in[1];
  const float* Wih = (const float*)d_in[2];
  const float* Whh = (const float*)d_in[3];
  const float* bih = (const float*)d_in[4];
  const float* bhh = (const float*)d_in[5];
  const float* Wp  = (const float*)d_in[6];
  const float* bp  = (const float*)d_in[7];
  const float* Wc  = (const float*)d_in[8];
  const float* bc  = (const float*)d_in[9];
  float* out = (float*)d_out;
  unsigned* wsu = (unsigned*)d_ws;
  float* wsf = (float*)d_ws + WSU;

  speller_init<<<32, NT, 0, stream>>>(LF, Emb, wsf, wsu);
  speller_main<<<NB, NT, 0, stream>>>(LF, Emb, Wih, Whh, bih, bhh, Wp, bp, Wc, bc,
                                      out, wsu, wsf);
}

// Round 2
// 7571.071 us; speedup vs baseline: 1.6469x; 1.5582x over previous
//
#include <hip/hip_runtime.h>
#include <math.h>
#include <stdint.h>

// ---------------------------------------------------------------------------
// Speller decoder, persistent kernel, 512 blocks x 256 threads.
// R5: parallel phase-4 merge. Previously the last-arriving logits block
// became "last arriver" for ALL 32 batches and ran the 32 per-batch
// softmax/argmax merges serially (~32 x 3-5us of single-block work per step
// while 511 blocks waited). Now: one arrival counter; batch b2's merge is
// owned by the FIXED block 256+b2; all 32 merges run concurrently.
// R4 (kept): single-pass attention, LF staged through LDS in 8-row tiles
// with register prefetch; online-softmax rescaled context. R3 (kept):
// relaxed AGENT-scope atomics through L3, monotonic counter barriers,
// LSTM fused into the gate GEMM.
// ---------------------------------------------------------------------------

#define NB 512
#define NT 256

constexpr int Tv = 1024, Vv = 5000, STEPS = 64;

// ---- u32 counter region (all monotonic, zeroed by init kernel) ----
constexpr int MCNT = 0;               // master barrier counter
constexpr int GEN  = 16;              // barrier generation
constexpr int GCNT = 64;              // 32 group counters, stride 16
constexpr int GFLG = 1024;            // 32 group release flags, stride 32
constexpr int ACNT = 2048;            // 32 attn-merge counters, stride 16
constexpr int LCNT = 2560;            // single logits-arrival counter
constexpr int WSU  = 4096;

// ---- float region offsets (wsf = (float*)ws + WSU) ----
constexpr int XH   = 0;                    // [32][1024] = emb(512) | ctx(512)
constexpr int HB   = XH + 32*1024;         // [2][32][512] h double-buffer
constexpr int HID  = HB + 2*32*512;        // [32][512]
constexpr int PART = HID + 32*512;         // [32][4][16][130] attn partials
constexpr int E3   = PART + 32*4*16*130;   // [32][1024] head-3 energies
constexpr int PM   = E3 + 32*1024;         // [32][256] chunk max
constexpr int PSUM = PM + 32*256;          // [32][256] chunk sumexp
constexpr int PIDX = PSUM + 32*256;        // [32][256] chunk argmax (int)
constexpr int MLS  = PIDX + 32*256;        // [32][2] (max, lse)

__device__ __forceinline__ float sigm(float x) { return 1.f / (1.f + expf(-x)); }

// ---- coherent (L3, sc0 sc1) access helpers: relaxed agent atomics ----
__device__ __forceinline__ float ld4(const float* p) {
  return __hip_atomic_load(const_cast<float*>(p), __ATOMIC_RELAXED, __HIP_MEMORY_SCOPE_AGENT);
}
__device__ __forceinline__ void st4(float* p, float v) {
  __hip_atomic_store(p, v, __ATOMIC_RELAXED, __HIP_MEMORY_SCOPE_AGENT);
}
__device__ __forceinline__ float2 ld8(const float* p) {
  unsigned long long u = __hip_atomic_load(
      reinterpret_cast<unsigned long long*>(const_cast<float*>(p)),
      __ATOMIC_RELAXED, __HIP_MEMORY_SCOPE_AGENT);
  union { unsigned long long u; float2 f; } c; c.u = u; return c.f;
}
__device__ __forceinline__ void st8(float* p, float2 v) {
  union { float2 f; unsigned long long u; } c; c.f = v;
  __hip_atomic_store(reinterpret_cast<unsigned long long*>(p), c.u,
                     __ATOMIC_RELAXED, __HIP_MEMORY_SCOPE_AGENT);
}
__device__ __forceinline__ int ld4i(const int* p) {
  return (int)__hip_atomic_load(reinterpret_cast<unsigned*>(const_cast<int*>(p)),
                                __ATOMIC_RELAXED, __HIP_MEMORY_SCOPE_AGENT);
}
__device__ __forceinline__ void st4i(int* p, int v) {
  __hip_atomic_store(reinterpret_cast<unsigned*>(p), (unsigned)v,
                     __ATOMIC_RELAXED, __HIP_MEMORY_SCOPE_AGENT);
}
__device__ __forceinline__ unsigned ld_rlx(unsigned* p) {
  return __hip_atomic_load(p, __ATOMIC_RELAXED, __HIP_MEMORY_SCOPE_AGENT);
}
__device__ __forceinline__ void st_rlx(unsigned* p, unsigned v) {
  __hip_atomic_store(p, v, __ATOMIC_RELAXED, __HIP_MEMORY_SCOPE_AGENT);
}
__device__ __forceinline__ unsigned add_rlx(unsigned* p, unsigned v) {
  return __hip_atomic_fetch_add(p, v, __ATOMIC_RELAXED, __HIP_MEMORY_SCOPE_AGENT);
}

// Device barrier: NO cache ops. __syncthreads drains vmcnt (sc1 stores are
// then in L3 = globally visible); counters/flags are relaxed sc1 atomics.
__device__ __forceinline__ void gsync(unsigned* wsu, int blk, int tid, unsigned& myGen) {
  __syncthreads();
  if (tid == 0) {
    const unsigned target = ++myGen;
    const int grp = blk >> 4;
    unsigned o = add_rlx(&wsu[GCNT + grp*16], 1u);
    if (o == target*16u - 1u) {
      unsigned o2 = add_rlx(&wsu[MCNT], 1u);
      if (o2 == target*32u - 1u) st_rlx(&wsu[GEN], target);
    }
    if ((blk & 15) == 0) {
      while (ld_rlx(&wsu[GEN]) != target) __builtin_amdgcn_s_sleep(2);
      st_rlx(&wsu[GFLG + grp*32], target);
    } else {
      while (ld_rlx(&wsu[GFLG + grp*32]) != target) __builtin_amdgcn_s_sleep(2);
    }
  }
  __syncthreads();
}

__global__ void speller_init(const float* __restrict__ LF, const float* __restrict__ Emb,
                             float* __restrict__ wsf, unsigned* __restrict__ wsu) {
  int b = blockIdx.x;
  for (int i = threadIdx.x; i < 512; i += NT) {
    st4(wsf + XH + b*1024 + i,       Emb[i]);                    // emb row 0
    st4(wsf + XH + b*1024 + 512 + i, LF[(size_t)b*Tv*512 + i]);  // ctx0 = LF[b,0,:]
    st4(wsf + HB + b*512 + i,        0.f);                       // h0 (buffer 0)
  }
  if (b == 0) for (int i = threadIdx.x; i < WSU; i += NT) st_rlx(wsu + i, 0u);
}

struct LdsA { float Wg[8][1536]; float gb[8]; };   // gate rows: i,i,f,f,g,g,o,o of units 2j,2j+1
struct LdsB { float Wc[20][512]; float Wp[2][1024]; float bcl[20]; float bpl[2]; };
union  LdsU { LdsA a; LdsB b; };

__launch_bounds__(NT, 2)
__global__ void speller_main(const float* __restrict__ LF, const float* __restrict__ Emb,
                             const float* __restrict__ Wih, const float* __restrict__ Whh,
                             const float* __restrict__ bih, const float* __restrict__ bhh,
                             const float* __restrict__ Wp,  const float* __restrict__ bp,
                             const float* __restrict__ Wc,  const float* __restrict__ bc,
                             float* __restrict__ out, unsigned* __restrict__ wsu,
                             float* __restrict__ wsf) {
  const int blk = blockIdx.x, tid = threadIdx.x;
  unsigned myGen = 0;
  __shared__ LdsU lds;
  __shared__ float scr[784];
  __shared__ int  sint[300];
  // LF tile buffer: 8 rows x 512 floats, rows padded to 516 (spreads banks
  // across the 8-row dimension: 516 % 32 == 4).
  __shared__ float lfl[8 * 516];

  // ---------------- one-time LDS weight preload (plain cached loads) -------
  if (blk < 256) {
    const int u0 = blk * 2;
    for (int idx = tid; idx < 8*1536; idx += NT) {
      int r = idx / 1536, k = idx - r*1536;
      int g = r >> 1, uu = r & 1;
      int row = g*512 + u0 + uu;
      lds.a.Wg[r][k] = (k < 1024) ? Wih[(size_t)row*1024 + k]
                                  : Whh[(size_t)row*512 + (k-1024)];
    }
    if (tid < 8) {
      int g = tid >> 1, uu = tid & 1, row = g*512 + u0 + uu;
      lds.a.gb[tid] = bih[row] + bhh[row];
    }
  } else {
    const int blk2 = blk - 256, v0 = blk2*20, rp0 = blk2*2;
    if (v0 < Vv) {
      for (int idx = tid; idx < 20*512; idx += NT) {
        int vi = idx >> 9, k = idx & 511;
        lds.b.Wc[vi][k] = Wc[(size_t)(v0+vi)*512 + k];
      }
      if (tid < 20) lds.b.bcl[tid] = bc[v0+tid];
    }
    for (int idx = tid; idx < 2048; idx += NT) {
      int r = idx >> 10, k = idx & 1023;
      lds.b.Wp[r][k] = Wp[(size_t)(rp0+r)*1024 + k];
    }
    if (tid < 2) lds.b.bpl[tid] = bp[rp0+tid];
  }
  __syncthreads();

  float c_reg[2][4];                 // cell state, lives in registers all run
#pragma unroll
  for (int uu = 0; uu < 2; ++uu)
#pragma unroll
    for (int i = 0; i < 4; ++i) c_reg[uu][i] = 0.f;
  float lgv[20];                     // logits carried phase4 -> next phase1

#pragma unroll 1
  for (int s = 0; s < STEPS; ++s) {
    const int rbuf = s & 1, wbuf = (s + 1) & 1;

    // ===== Phase 1: gates GEMM + fused LSTM (blk<256) | out-write (>=256) ==
    if (blk < 256) {
      const int u0 = blk * 2;
      const int slot = tid >> 5, ks = tid & 31, b0 = slot * 4;
      float acc[8][4];
#pragma unroll
      for (int r = 0; r < 8; ++r)
#pragma unroll
        for (int i = 0; i < 4; ++i) acc[r][i] = 0.f;
      const float* x1 = wsf + XH;                  // [32][1024] emb|ctx
      const float* x2 = wsf + HB + rbuf*16384;     // [32][512]  h
#pragma unroll 2
      for (int q = 0; q < 8; ++q) {                // k in [0,1024): emb|ctx
        const int kq = q*32 + ks;
        float2 xa[4], xb[4];
#pragma unroll
        for (int i = 0; i < 4; ++i) {
          const float* p = x1 + (size_t)(b0+i)*1024 + kq*4;
          xa[i] = ld8(p); xb[i] = ld8(p + 2);
        }
#pragma unroll
        for (int r = 0; r < 8; ++r) {
          float4 wv = *(const float4*)(&lds.a.Wg[r][kq*4]);
#pragma unroll
          for (int i = 0; i < 4; ++i)
            acc[r][i] += wv.x*xa[i].x + wv.y*xa[i].y + wv.z*xb[i].x + wv.w*xb[i].y;
        }
      }
#pragma unroll 2
      for (int q = 0; q < 4; ++q) {                // k in [1024,1536): h
        const int kq = q*32 + ks;
        float2 xa[4], xb[4];
#pragma unroll
        for (int i = 0; i < 4; ++i) {
          const float* p = x2 + (size_t)(b0+i)*512 + kq*4;
          xa[i] = ld8(p); xb[i] = ld8(p + 2);
        }
#pragma unroll
        for (int r = 0; r < 8; ++r) {
          float4 wv = *(const float4*)(&lds.a.Wg[r][1024 + kq*4]);
#pragma unroll
          for (int i = 0; i < 4; ++i)
            acc[r][i] += wv.x*xa[i].x + wv.y*xa[i].y + wv.z*xb[i].x + wv.w*xb[i].y;
        }
      }
#pragma unroll
      for (int r = 0; r < 8; ++r)
#pragma unroll
        for (int i = 0; i < 4; ++i) {
          float v = acc[r][i];
          v += __shfl_xor(v, 16); v += __shfl_xor(v, 8); v += __shfl_xor(v, 4);
          v += __shfl_xor(v, 2);  v += __shfl_xor(v, 1);
          acc[r][i] = v + lds.a.gb[r];
        }
      // fused LSTM pointwise (rows: i=uu, f=2+uu, g=4+uu, o=6+uu)
      float hnew[2][4];
#pragma unroll
      for (int uu = 0; uu < 2; ++uu)
#pragma unroll
        for (int i = 0; i < 4; ++i) {
          float cn = sigm(acc[2+uu][i]) * c_reg[uu][i]
                   + sigm(acc[uu][i]) * tanhf(acc[4+uu][i]);
          c_reg[uu][i] = cn;
          hnew[uu][i] = sigm(acc[6+uu][i]) * tanhf(cn);
        }
      if (ks == 0) {
#pragma unroll
        for (int i = 0; i < 4; ++i)
          st8(wsf + HB + wbuf*16384 + (size_t)(b0+i)*512 + u0,
              make_float2(hnew[0][i], hnew[1][i]));
      }
    } else if (s > 0) {
      const int blk2 = blk - 256;
      if (blk2 < 250) {
        const int v0 = blk2 * 20, bb = tid >> 3, ks = tid & 7;
        if (ks == 0) {
          float2 ml = ld8(wsf + MLS + 2*bb);
          float sub = ml.x + ml.y;
#pragma unroll
          for (int vi = 0; vi < 20; ++vi)
            out[(size_t)(s-1)*160000 + (size_t)bb*5000 + v0 + vi] = lgv[vi] - sub;
        }
      }
    }
    gsync(wsu, blk, tid, myGen);

    // ============ Phase 2: attention, single-pass LF via LDS tiles ==========
    // Block (b,tc) owns t in [tc*64, tc*64+64). 8 tiles of 8 t-rows each are
    // staged through lfl with one-ahead register prefetch; energies and the
    // online-rescaled context accumulation both read lfl. LF is read ONCE.
    {
      const int b = blk >> 4, tc = blk & 15;
      const int t0 = tc * 64;
      float* hs = scr;  // [512] decoder state
      {
        float2 hv = ld8(wsf + HB + wbuf*16384 + (size_t)b*512 + tid*2);
        hs[tid*2] = hv.x; hs[tid*2+1] = hv.y;
      }
      const int w = tid >> 6, ln = tid & 63;   // wave <-> head
      const int tt = ln >> 3, kk = ln & 7;     // 8 lanes per t-row for energy
      const int rr = tid >> 7, cc = (tid & 127) * 4;   // staging coords
      // running per-head state; lane ln owns context dims w*128+2ln, +1
      float m = -1e30f, l = 0.f, c0 = 0.f, c1 = 0.f;
      const float4* lfg = (const float4*)(LF + ((size_t)(b*Tv + t0))*512);
      float4 pf0 = lfg[tid], pf1 = lfg[256 + tid],
             pf2 = lfg[512 + tid], pf3 = lfg[768 + tid];
#pragma unroll 1
      for (int it = 0; it < 8; ++it) {
        __syncthreads();               // lfl free (prev tile consumed); hs ready
        *(float4*)&lfl[(rr    )*516 + cc] = pf0;
        *(float4*)&lfl[(rr + 2)*516 + cc] = pf1;
        *(float4*)&lfl[(rr + 4)*516 + cc] = pf2;
        *(float4*)&lfl[(rr + 6)*516 + cc] = pf3;
        if (it < 7) {                  // prefetch next tile into registers
          const float4* g2 = lfg + (size_t)(it + 1) * 1024;
          pf0 = g2[tid]; pf1 = g2[256 + tid]; pf2 = g2[512 + tid]; pf3 = g2[768 + tid];
        }
        __syncthreads();               // lfl tile ready
        // ---- energy for t = t0 + it*8 + tt (8 lanes x 16 floats each) ----
        float e = 0.f;
        {
          const float4* lp = (const float4*)&lfl[tt*516 + w*128 + kk*16];
          const float4* hp = (const float4*)&hs[w*128 + kk*16];
#pragma unroll
          for (int q = 0; q < 4; ++q) {
            float4 f = lp[q], hh = hp[q];
            e += f.x*hh.x + f.y*hh.y + f.z*hh.z + f.w*hh.w;
          }
        }
        e += __shfl_xor(e, 1); e += __shfl_xor(e, 2); e += __shfl_xor(e, 4);
        if (w == 3 && kk == 0)
          st4(wsf + E3 + (size_t)b*1024 + t0 + it*8 + tt, e);
        // ---- broadcast the tile's 8 energies to every lane of the wave ----
        float e8[8];
#pragma unroll
        for (int j = 0; j < 8; ++j) e8[j] = __shfl(e, j*8);
        float pm = fmaxf(fmaxf(fmaxf(e8[0],e8[1]), fmaxf(e8[2],e8[3])),
                         fmaxf(fmaxf(e8[4],e8[5]), fmaxf(e8[6],e8[7])));
        float mn = fmaxf(m, pm);
        float rs = expf(m - mn);       // first tile: exp(-huge) == 0
        l *= rs; c0 *= rs; c1 *= rs;
        m = mn;
        const float* crow = &lfl[w*128 + 2*ln];
#pragma unroll
        for (int j = 0; j < 8; ++j) {
          float p = expf(e8[j] - m);
          l += p;
          float2 f = *(const float2*)(crow + j*516);
          c0 += p*f.x; c1 += p*f.y;
        }
      }
      // ---- chunk partials (identical layout to R3) ----
      float* pr = wsf + PART + (size_t)((b*4 + w)*16 + tc)*130;
      st8(pr + 2 + 2*ln, make_float2(c0, c1));
      if (ln == 0) st8(pr, make_float2(m, l));
      __syncthreads();   // drains vmcnt: all this block's partials are in L3
      if (tid == 0) {
        unsigned old = add_rlx(&wsu[ACNT + b*16], 1u);
        sint[0] = (old == (unsigned)(s*16 + 15));
      }
      __syncthreads();
      if (sint[0]) {                       // last arriver merges the 16 chunks
        const int w2 = tid >> 6, ln2 = tid & 63;
        const float* pb = wsf + PART + (size_t)(b*4 + w2)*16*130;
        float M = -1e30f;
        float mv[16], lv[16];
#pragma unroll
        for (int i = 0; i < 16; ++i) { float2 t = ld8(pb + i*130); mv[i] = t.x; lv[i] = t.y; M = fmaxf(M, t.x); }
        float L = 0.f;
        float sc[16];
#pragma unroll
        for (int i = 0; i < 16; ++i) { sc[i] = expf(mv[i] - M); L += lv[i] * sc[i]; }
        float cc0 = 0.f, cc1 = 0.f;
#pragma unroll
        for (int i = 0; i < 16; ++i) {
          float2 cx = ld8(pb + i*130 + 2 + 2*ln2);
          cc0 += sc[i]*cx.x; cc1 += sc[i]*cx.y;
        }
        float invL = 1.f / L;
        st8(wsf + XH + (size_t)b*1024 + 512 + w2*128 + 2*ln2,
            make_float2(cc0*invL, cc1*invL));
        if (ln2 == 0) { scr[768 + w2*2] = M; scr[769 + w2*2] = L; }
        __syncthreads();
        float M3 = scr[768 + 6], iL3 = 1.f / scr[768 + 7];
        for (int i = tid; i < 1024; i += NT)
          out[(size_t)10240000 + ((size_t)(s*32 + b))*1024 + i] =
              expf(ld4(wsf + E3 + (size_t)b*1024 + i) - M3) * iL3;
      }
    }
    gsync(wsu, blk, tid, myGen);

    // ============ Phase 3: MLP hid = relu([h,ctx] @ Wp^T + bp) ===============
    if (blk >= 256) {
      const int blk2 = blk - 256, rp0 = blk2*2;
      const int bb = tid & 31, ks = tid >> 5;        // 8 K-windows of 128
      const float* xr = (ks < 4) ? (wsf + HB + wbuf*16384 + (size_t)bb*512 + ks*128)
                                 : (wsf + XH + (size_t)bb*1024 + (ks-4)*128 + 512);
      const int kb = ks * 128;
      const float4* w0 = (const float4*)(&lds.b.Wp[0][kb]);
      const float4* w1 = (const float4*)(&lds.b.Wp[1][kb]);
      float a0 = 0.f, a1 = 0.f;
#pragma unroll 8
      for (int q = 0; q < 32; ++q) {
        float2 xva = ld8(xr + q*4), xvb = ld8(xr + q*4 + 2);
        float4 wv0 = w0[q], wv1 = w1[q];
        a0 += wv0.x*xva.x + wv0.y*xva.y + wv0.z*xvb.x + wv0.w*xvb.y;
        a1 += wv1.x*xva.x + wv1.y*xva.y + wv1.z*xvb.x + wv1.w*xvb.y;
      }
      scr[ks*32 + bb] = a0; scr[256 + ks*32 + bb] = a1;
      __syncthreads();
      if (tid < 64) {
        int r = tid >> 5, b2 = tid & 31;
        float ssum = 0.f;
#pragma unroll
        for (int j = 0; j < 8; ++j) ssum += scr[r*256 + j*32 + b2];
        ssum += lds.b.bpl[r];
        st4(wsf + HID + (size_t)b2*512 + rp0 + r, fmaxf(ssum, 0.f));
      }
      __syncthreads();
    }
    gsync(wsu, blk, tid, myGen);

    // ============ Phase 4: logits + softmax/argmax partials; parallel merge ==
    if (blk >= 256) {
      const int blk2 = blk - 256;
      if (blk2 < 250) {
        const int v0 = blk2 * 20;
        const int bb = tid >> 3, ks = tid & 7;       // interleaved K chunks
        float4 xr[16];
        const float* hb = wsf + HID + (size_t)bb*512;
#pragma unroll
        for (int q = 0; q < 16; ++q) {
          const float* p = hb + (q*8 + ks)*4;
          float2 a = ld8(p), b2v = ld8(p + 2);
          xr[q] = make_float4(a.x, a.y, b2v.x, b2v.y);
        }
#pragma unroll
        for (int vi = 0; vi < 20; ++vi) {
          float a = 0.f;
#pragma unroll
          for (int q = 0; q < 16; ++q) {
            float4 wv = *(const float4*)(&lds.b.Wc[vi][(q*8 + ks)*4]);
            a += wv.x*xr[q].x + wv.y*xr[q].y + wv.z*xr[q].z + wv.w*xr[q].w;
          }
          a += __shfl_xor(a, 1); a += __shfl_xor(a, 2); a += __shfl_xor(a, 4);
          lgv[vi] = a + lds.b.bcl[vi];
        }
        float mych = lgv[0]; int ami = 0;
#pragma unroll
        for (int vi = 1; vi < 20; ++vi)
          if (lgv[vi] > mych) { mych = lgv[vi]; ami = vi; }
        float sume = 0.f;
#pragma unroll
        for (int vi = 0; vi < 20; ++vi) sume += expf(lgv[vi] - mych);
        if (ks == 0) {
          st4(wsf + PM + bb*256 + blk2, mych);
          st4(wsf + PSUM + bb*256 + blk2, sume);
          st4i((int*)(wsf + PIDX) + bb*256 + blk2, v0 + ami);
        }
      }
      __syncthreads();   // drain: this block's partials are in L3
      if (tid == 0 && blk2 < 250) add_rlx(&wsu[LCNT], 1u);
      // ---- parallel merge: block 256+b2 owns batch b2 (32 concurrent) ----
      if (blk2 < 32) {
        const int b2 = blk2;
        if (tid == 0) {
          while (ld_rlx(&wsu[LCNT]) < (unsigned)((s + 1) * 250))
            __builtin_amdgcn_s_sleep(2);
        }
        __syncthreads();               // all 250 partials visible
        float mv = -1e30f, sv = 0.f; int iv = 0x7fffffff;
        if (tid < 250) {
          mv = ld4(wsf + PM + b2*256 + tid);
          sv = ld4(wsf + PSUM + b2*256 + tid);
          iv = ld4i((const int*)(wsf + PIDX) + b2*256 + tid);
        }
        scr[tid] = mv; sint[40 + tid] = iv;
        __syncthreads();
        for (int off = 128; off; off >>= 1) {
          if (tid < off) {
            float m2 = scr[tid + off]; int i2 = sint[40 + tid + off];
            if (m2 > scr[tid] || (m2 == scr[tid] && i2 < sint[40 + tid])) {
              scr[tid] = m2; sint[40 + tid] = i2;
            }
          }
          __syncthreads();
        }
        float M = scr[0]; int tok = sint[40];
        __syncthreads();
        scr[tid] = sv * expf(mv - M);
        __syncthreads();
        for (int off = 128; off; off >>= 1) {
          if (tid < off) scr[tid] += scr[tid + off];
          __syncthreads();
        }
        if (tid == 0) st8(wsf + MLS + 2*b2, make_float2(M, logf(scr[0])));
        for (int i = tid; i < 256; i += NT) {
          const float2* er = (const float2*)(Emb + (size_t)tok*512);
          st8(wsf + XH + (size_t)b2*1024 + 2*i, er[i]);
        }
      }
    }
    gsync(wsu, blk, tid, myGen);
  }

  // ---------------- epilogue: step 63's log-softmax from registers ----------
  if (blk >= 256) {
    const int blk2 = blk - 256;
    if (blk2 < 250) {
      const int v0 = blk2 * 20, bb = tid >> 3, ks = tid & 7;
      if (ks == 0) {
        float2 ml = ld8(wsf + MLS + 2*bb);
        float sub = ml.x + ml.y;
#pragma unroll
        for (int vi = 0; vi < 20; ++vi)
          out[(size_t)63*160000 + (size_t)bb*5000 + v0 + vi] = lgv[vi] - sub;
      }
    }
  }
}

extern "C" void kernel_launch(void* const* d_in, const int* in_sizes, int n_in,
                              void* d_out, int out_size, void* d_ws, size_t ws_size,
                              hipStream_t stream) {
  (void)in_sizes; (void)n_in; (void)out_size; (void)ws_size;
  const float* LF  = (const float*)d_in[0];
  const float* Emb = (const float*)d_in[1];
  const float* Wih = (const float*)d_in[2];
  const float* Whh = (const float*)d_in[3];
  const float* bih = (const float*)d_in[4];
  const float* bhh = (const float*)d_in[5];
  const float* Wp  = (const float*)d_in[6];
  const float* bp  = (const float*)d_in[7];
  const float* Wc  = (const float*)d_in[8];
  const float* bc  = (const float*)d_in[9];
  float* out = (float*)d_out;
  unsigned* wsu = (unsigned*)d_ws;
  float* wsf = (float*)d_ws + WSU;

  speller_init<<<32, NT, 0, stream>>>(LF, Emb, wsf, wsu);
  speller_main<<<NB, NT, 0, stream>>>(LF, Emb, Wih, Whh, bih, bhh, Wp, bp, Wc, bc,
                                      out, wsu, wsf);
}

// Round 4
// 6741.741 us; speedup vs baseline: 1.8495x; 1.1230x over previous
//
#include <hip/hip_runtime.h>
#include <math.h>
#include <stdint.h>

// ---------------------------------------------------------------------------
// Speller decoder, persistent kernel, 512 blocks x 256 threads.
// R7 = R6 with two fixes:
//  (a) reduce-scatter butterfly exchanged the wrong half (shuffled the KEPT
//      value instead of the SENT value) -> context scrambled, absmax 1.7.
//      Now: keep = bit? c[j+o]:c[j]; send = bit? c[j]:c[j+o];
//      c[j] = keep + shfl_xor(send, o). Lane aln ends owning dim aln.
//  (b) ch-loop fully unrolled so lfr[] indices are compile-time (runtime
//      index would spill the 128-VGPR LF slice to scratch, rule #20).
// R6: LF register-resident (64x512 chunk = 128 VGPRs/thread, loaded once;
// phase-2 attention does zero LF memory traffic). R5: parallel per-batch
// phase-4 merge. R3: relaxed AGENT-scope atomics through L3, monotonic
// counter barriers, LSTM fused into the gate GEMM.
// ---------------------------------------------------------------------------

#define NB 512
#define NT 256

constexpr int Tv = 1024, Vv = 5000, STEPS = 64;

// ---- u32 counter region (all monotonic, zeroed by init kernel) ----
constexpr int MCNT = 0;               // master barrier counter
constexpr int GEN  = 16;              // barrier generation
constexpr int GCNT = 64;              // 32 group counters, stride 16
constexpr int GFLG = 1024;            // 32 group release flags, stride 32
constexpr int ACNT = 2048;            // 32 attn-merge counters, stride 16
constexpr int LCNT = 2560;            // single logits-arrival counter
constexpr int WSU  = 4096;

// ---- float region offsets (wsf = (float*)ws + WSU) ----
constexpr int XH   = 0;                    // [32][1024] = emb(512) | ctx(512)
constexpr int HB   = XH + 32*1024;         // [2][32][512] h double-buffer
constexpr int HID  = HB + 2*32*512;        // [32][512]
constexpr int PART = HID + 32*512;         // [32][4][16][130] attn partials
constexpr int E3   = PART + 32*4*16*130;   // [32][1024] head-3 energies
constexpr int PM   = E3 + 32*1024;         // [32][256] chunk max
constexpr int PSUM = PM + 32*256;          // [32][256] chunk sumexp
constexpr int PIDX = PSUM + 32*256;        // [32][256] chunk argmax (int)
constexpr int MLS  = PIDX + 32*256;        // [32][2] (max, lse)

__device__ __forceinline__ float sigm(float x) { return 1.f / (1.f + expf(-x)); }

// ---- coherent (L3, sc0 sc1) access helpers: relaxed agent atomics ----
__device__ __forceinline__ float ld4(const float* p) {
  return __hip_atomic_load(const_cast<float*>(p), __ATOMIC_RELAXED, __HIP_MEMORY_SCOPE_AGENT);
}
__device__ __forceinline__ void st4(float* p, float v) {
  __hip_atomic_store(p, v, __ATOMIC_RELAXED, __HIP_MEMORY_SCOPE_AGENT);
}
__device__ __forceinline__ float2 ld8(const float* p) {
  unsigned long long u = __hip_atomic_load(
      reinterpret_cast<unsigned long long*>(const_cast<float*>(p)),
      __ATOMIC_RELAXED, __HIP_MEMORY_SCOPE_AGENT);
  union { unsigned long long u; float2 f; } c; c.u = u; return c.f;
}
__device__ __forceinline__ void st8(float* p, float2 v) {
  union { float2 f; unsigned long long u; } c; c.f = v;
  __hip_atomic_store(reinterpret_cast<unsigned long long*>(p), c.u,
                     __ATOMIC_RELAXED, __HIP_MEMORY_SCOPE_AGENT);
}
__device__ __forceinline__ int ld4i(const int* p) {
  return (int)__hip_atomic_load(reinterpret_cast<unsigned*>(const_cast<int*>(p)),
                                __ATOMIC_RELAXED, __HIP_MEMORY_SCOPE_AGENT);
}
__device__ __forceinline__ void st4i(int* p, int v) {
  __hip_atomic_store(reinterpret_cast<unsigned*>(p), (unsigned)v,
                     __ATOMIC_RELAXED, __HIP_MEMORY_SCOPE_AGENT);
}
__device__ __forceinline__ unsigned ld_rlx(unsigned* p) {
  return __hip_atomic_load(p, __ATOMIC_RELAXED, __HIP_MEMORY_SCOPE_AGENT);
}
__device__ __forceinline__ void st_rlx(unsigned* p, unsigned v) {
  __hip_atomic_store(p, v, __ATOMIC_RELAXED, __HIP_MEMORY_SCOPE_AGENT);
}
__device__ __forceinline__ unsigned add_rlx(unsigned* p, unsigned v) {
  return __hip_atomic_fetch_add(p, v, __ATOMIC_RELAXED, __HIP_MEMORY_SCOPE_AGENT);
}

// Device barrier: NO cache ops. __syncthreads drains vmcnt (sc1 stores are
// then in L3 = globally visible); counters/flags are relaxed sc1 atomics.
__device__ __forceinline__ void gsync(unsigned* wsu, int blk, int tid, unsigned& myGen) {
  __syncthreads();
  if (tid == 0) {
    const unsigned target = ++myGen;
    const int grp = blk >> 4;
    unsigned o = add_rlx(&wsu[GCNT + grp*16], 1u);
    if (o == target*16u - 1u) {
      unsigned o2 = add_rlx(&wsu[MCNT], 1u);
      if (o2 == target*32u - 1u) st_rlx(&wsu[GEN], target);
    }
    if ((blk & 15) == 0) {
      while (ld_rlx(&wsu[GEN]) != target) __builtin_amdgcn_s_sleep(2);
      st_rlx(&wsu[GFLG + grp*32], target);
    } else {
      while (ld_rlx(&wsu[GFLG + grp*32]) != target) __builtin_amdgcn_s_sleep(2);
    }
  }
  __syncthreads();
}

__global__ void speller_init(const float* __restrict__ LF, const float* __restrict__ Emb,
                             float* __restrict__ wsf, unsigned* __restrict__ wsu) {
  int b = blockIdx.x;
  for (int i = threadIdx.x; i < 512; i += NT) {
    st4(wsf + XH + b*1024 + i,       Emb[i]);                    // emb row 0
    st4(wsf + XH + b*1024 + 512 + i, LF[(size_t)b*Tv*512 + i]);  // ctx0 = LF[b,0,:]
    st4(wsf + HB + b*512 + i,        0.f);                       // h0 (buffer 0)
  }
  if (b == 0) for (int i = threadIdx.x; i < WSU; i += NT) st_rlx(wsu + i, 0u);
}

struct LdsA { float Wg[8][1536]; float gb[8]; };   // gate rows: i,i,f,f,g,g,o,o of units 2j,2j+1
struct LdsB { float Wc[20][512]; float Wp[2][1024]; float bcl[20]; float bpl[2]; };
union  LdsU { LdsA a; LdsB b; };

__launch_bounds__(NT, 2)
__global__ void speller_main(const float* __restrict__ LF, const float* __restrict__ Emb,
                             const float* __restrict__ Wih, const float* __restrict__ Whh,
                             const float* __restrict__ bih, const float* __restrict__ bhh,
                             const float* __restrict__ Wp,  const float* __restrict__ bp,
                             const float* __restrict__ Wc,  const float* __restrict__ bc,
                             float* __restrict__ out, unsigned* __restrict__ wsu,
                             float* __restrict__ wsf) {
  const int blk = blockIdx.x, tid = threadIdx.x;
  unsigned myGen = 0;
  __shared__ LdsU lds;
  __shared__ float scr[784];
  __shared__ int  sint[300];

  const int ab = blk >> 4, atc = blk & 15;         // attention chunk identity
  const int aw = tid >> 6, aln = tid & 63;         // head / t-row lane

  // ---- persistent LF slice: LF[ab, atc*64+aln, aw*128 .. +127] ----
  float4 lfr[32];
  {
    const float4* src = (const float4*)(LF +
        (((size_t)ab*Tv + atc*64 + aln)*512 + aw*128));
#pragma unroll
    for (int q = 0; q < 32; ++q) lfr[q] = src[q];
  }

  // ---------------- one-time LDS weight preload (plain cached loads) -------
  if (blk < 256) {
    const int u0 = blk * 2;
    for (int idx = tid; idx < 8*1536; idx += NT) {
      int r = idx / 1536, k = idx - r*1536;
      int g = r >> 1, uu = r & 1;
      int row = g*512 + u0 + uu;
      lds.a.Wg[r][k] = (k < 1024) ? Wih[(size_t)row*1024 + k]
                                  : Whh[(size_t)row*512 + (k-1024)];
    }
    if (tid < 8) {
      int g = tid >> 1, uu = tid & 1, row = g*512 + u0 + uu;
      lds.a.gb[tid] = bih[row] + bhh[row];
    }
  } else {
    const int blk2 = blk - 256, v0 = blk2*20, rp0 = blk2*2;
    if (v0 < Vv) {
      for (int idx = tid; idx < 20*512; idx += NT) {
        int vi = idx >> 9, k = idx & 511;
        lds.b.Wc[vi][k] = Wc[(size_t)(v0+vi)*512 + k];
      }
      if (tid < 20) lds.b.bcl[tid] = bc[v0+tid];
    }
    for (int idx = tid; idx < 2048; idx += NT) {
      int r = idx >> 10, k = idx & 1023;
      lds.b.Wp[r][k] = Wp[(size_t)(rp0+r)*1024 + k];
    }
    if (tid < 2) lds.b.bpl[tid] = bp[rp0+tid];
  }
  __syncthreads();

  float c_reg[2][4];                 // cell state, lives in registers all run
#pragma unroll
  for (int uu = 0; uu < 2; ++uu)
#pragma unroll
    for (int i = 0; i < 4; ++i) c_reg[uu][i] = 0.f;
  float lgv[20];                     // logits carried phase4 -> next phase1

#pragma unroll 1
  for (int s = 0; s < STEPS; ++s) {
    const int rbuf = s & 1, wbuf = (s + 1) & 1;

    // ===== Phase 1: gates GEMM + fused LSTM (blk<256) | out-write (>=256) ==
    if (blk < 256) {
      const int u0 = blk * 2;
      const int slot = tid >> 5, ks = tid & 31, b0 = slot * 4;
      float acc[8][4];
#pragma unroll
      for (int r = 0; r < 8; ++r)
#pragma unroll
        for (int i = 0; i < 4; ++i) acc[r][i] = 0.f;
      const float* x1 = wsf + XH;                  // [32][1024] emb|ctx
      const float* x2 = wsf + HB + rbuf*16384;     // [32][512]  h
#pragma unroll 2
      for (int q = 0; q < 8; ++q) {                // k in [0,1024): emb|ctx
        const int kq = q*32 + ks;
        float2 xa[4], xb[4];
#pragma unroll
        for (int i = 0; i < 4; ++i) {
          const float* p = x1 + (size_t)(b0+i)*1024 + kq*4;
          xa[i] = ld8(p); xb[i] = ld8(p + 2);
        }
#pragma unroll
        for (int r = 0; r < 8; ++r) {
          float4 wv = *(const float4*)(&lds.a.Wg[r][kq*4]);
#pragma unroll
          for (int i = 0; i < 4; ++i)
            acc[r][i] += wv.x*xa[i].x + wv.y*xa[i].y + wv.z*xb[i].x + wv.w*xb[i].y;
        }
      }
#pragma unroll 2
      for (int q = 0; q < 4; ++q) {                // k in [1024,1536): h
        const int kq = q*32 + ks;
        float2 xa[4], xb[4];
#pragma unroll
        for (int i = 0; i < 4; ++i) {
          const float* p = x2 + (size_t)(b0+i)*512 + kq*4;
          xa[i] = ld8(p); xb[i] = ld8(p + 2);
        }
#pragma unroll
        for (int r = 0; r < 8; ++r) {
          float4 wv = *(const float4*)(&lds.a.Wg[r][1024 + kq*4]);
#pragma unroll
          for (int i = 0; i < 4; ++i)
            acc[r][i] += wv.x*xa[i].x + wv.y*xa[i].y + wv.z*xb[i].x + wv.w*xb[i].y;
        }
      }
#pragma unroll
      for (int r = 0; r < 8; ++r)
#pragma unroll
        for (int i = 0; i < 4; ++i) {
          float v = acc[r][i];
          v += __shfl_xor(v, 16); v += __shfl_xor(v, 8); v += __shfl_xor(v, 4);
          v += __shfl_xor(v, 2);  v += __shfl_xor(v, 1);
          acc[r][i] = v + lds.a.gb[r];
        }
      // fused LSTM pointwise (rows: i=uu, f=2+uu, g=4+uu, o=6+uu)
      float hnew[2][4];
#pragma unroll
      for (int uu = 0; uu < 2; ++uu)
#pragma unroll
        for (int i = 0; i < 4; ++i) {
          float cn = sigm(acc[2+uu][i]) * c_reg[uu][i]
                   + sigm(acc[uu][i]) * tanhf(acc[4+uu][i]);
          c_reg[uu][i] = cn;
          hnew[uu][i] = sigm(acc[6+uu][i]) * tanhf(cn);
        }
      if (ks == 0) {
#pragma unroll
        for (int i = 0; i < 4; ++i)
          st8(wsf + HB + wbuf*16384 + (size_t)(b0+i)*512 + u0,
              make_float2(hnew[0][i], hnew[1][i]));
      }
    } else if (s > 0) {
      const int blk2 = blk - 256;
      if (blk2 < 250) {
        const int v0 = blk2 * 20, bb = tid >> 3, ks = tid & 7;
        if (ks == 0) {
          float2 ml = ld8(wsf + MLS + 2*bb);
          float sub = ml.x + ml.y;
#pragma unroll
          for (int vi = 0; vi < 20; ++vi)
            out[(size_t)(s-1)*160000 + (size_t)bb*5000 + v0 + vi] = lgv[vi] - sub;
        }
      }
    }
    gsync(wsu, blk, tid, myGen);

    // ============ Phase 2: attention from register-resident LF ==============
    // Lane (aw,aln) owns t-row t0+aln of head aw. Energy = in-register dot
    // vs h (LDS broadcast). One exp per lane. Context via 2x 64-dim
    // reduce-scatter (keep/send recursive halving); lane aln ends owning
    // ctx dim ch*64+aln -> position pr+2+ch*64+aln (position 2+j <-> dim j,
    // same mapping the merge expects).
    {
      float* hs = scr;  // [512] decoder state
      {
        float2 hv = ld8(wsf + HB + wbuf*16384 + (size_t)ab*512 + tid*2);
        hs[tid*2] = hv.x; hs[tid*2+1] = hv.y;
      }
      __syncthreads();
      float e = 0.f;
      {
        const float4* hp = (const float4*)(hs + aw*128);
#pragma unroll
        for (int q = 0; q < 32; ++q) {
          float4 f = lfr[q], hh = hp[q];
          e += f.x*hh.x + f.y*hh.y + f.z*hh.z + f.w*hh.w;
        }
      }
      float m = e;
#pragma unroll
      for (int off = 32; off; off >>= 1) m = fmaxf(m, __shfl_xor(m, off));
      float p = expf(e - m);
      float l = p;
#pragma unroll
      for (int off = 32; off; off >>= 1) l += __shfl_xor(l, off);
      if (aw == 3) st4(wsf + E3 + (size_t)ab*1024 + atc*64 + aln, e);
      float* pr = wsf + PART + (size_t)((ab*4 + aw)*16 + atc)*130;
#pragma unroll
      for (int ch = 0; ch < 2; ++ch) {             // fully unrolled: lfr idx static
        float c[64];
#pragma unroll
        for (int q = 0; q < 16; ++q) {
          float4 f = lfr[ch*16 + q];
          c[4*q+0] = p*f.x; c[4*q+1] = p*f.y; c[4*q+2] = p*f.z; c[4*q+3] = p*f.w;
        }
#pragma unroll
        for (int o = 32; o >= 1; o >>= 1) {
#pragma unroll
          for (int j = 0; j < 32; ++j) {
            if (j < o) {
              float keep = (aln & o) ? c[j + o] : c[j];
              float send = (aln & o) ? c[j] : c[j + o];
              c[j] = keep + __shfl_xor(send, o);
            }
          }
        }
        st4(pr + 2 + ch*64 + aln, c[0]);
      }
      if (aln == 0) st8(pr, make_float2(m, l));
      __syncthreads();   // drains vmcnt: all this block's partials are in L3
      if (tid == 0) {
        unsigned old = add_rlx(&wsu[ACNT + ab*16], 1u);
        sint[0] = (old == (unsigned)(s*16 + 15));
      }
      __syncthreads();
      if (sint[0]) {                       // last arriver merges the 16 chunks
        const int w2 = tid >> 6, ln2 = tid & 63;
        const float* pb = wsf + PART + (size_t)(ab*4 + w2)*16*130;
        float M = -1e30f;
        float mv[16], lv[16];
#pragma unroll
        for (int i = 0; i < 16; ++i) { float2 t = ld8(pb + i*130); mv[i] = t.x; lv[i] = t.y; M = fmaxf(M, t.x); }
        float L = 0.f;
        float sc[16];
#pragma unroll
        for (int i = 0; i < 16; ++i) { sc[i] = expf(mv[i] - M); L += lv[i] * sc[i]; }
        float cc0 = 0.f, cc1 = 0.f;
#pragma unroll
        for (int i = 0; i < 16; ++i) {
          float2 cx = ld8(pb + i*130 + 2 + 2*ln2);
          cc0 += sc[i]*cx.x; cc1 += sc[i]*cx.y;
        }
        float invL = 1.f / L;
        st8(wsf + XH + (size_t)ab*1024 + 512 + w2*128 + 2*ln2,
            make_float2(cc0*invL, cc1*invL));
        if (ln2 == 0) { scr[768 + w2*2] = M; scr[769 + w2*2] = L; }
        __syncthreads();
        float M3 = scr[768 + 6], iL3 = 1.f / scr[768 + 7];
        for (int i = tid; i < 1024; i += NT)
          out[(size_t)10240000 + ((size_t)(s*32 + ab))*1024 + i] =
              expf(ld4(wsf + E3 + (size_t)ab*1024 + i) - M3) * iL3;
      }
    }
    gsync(wsu, blk, tid, myGen);

    // ============ Phase 3: MLP hid = relu([h,ctx] @ Wp^T + bp) ===============
    if (blk >= 256) {
      const int blk2 = blk - 256, rp0 = blk2*2;
      const int bb = tid & 31, ks = tid >> 5;        // 8 K-windows of 128
      const float* xr = (ks < 4) ? (wsf + HB + wbuf*16384 + (size_t)bb*512 + ks*128)
                                 : (wsf + XH + (size_t)bb*1024 + (ks-4)*128 + 512);
      const int kb = ks * 128;
      const float4* w0 = (const float4*)(&lds.b.Wp[0][kb]);
      const float4* w1 = (const float4*)(&lds.b.Wp[1][kb]);
      float a0 = 0.f, a1 = 0.f;
#pragma unroll 8
      for (int q = 0; q < 32; ++q) {
        float2 xva = ld8(xr + q*4), xvb = ld8(xr + q*4 + 2);
        float4 wv0 = w0[q], wv1 = w1[q];
        a0 += wv0.x*xva.x + wv0.y*xva.y + wv0.z*xvb.x + wv0.w*xvb.y;
        a1 += wv1.x*xva.x + wv1.y*xva.y + wv1.z*xvb.x + wv1.w*xvb.y;
      }
      scr[ks*32 + bb] = a0; scr[256 + ks*32 + bb] = a1;
      __syncthreads();
      if (tid < 64) {
        int r = tid >> 5, b2 = tid & 31;
        float ssum = 0.f;
#pragma unroll
        for (int j = 0; j < 8; ++j) ssum += scr[r*256 + j*32 + b2];
        ssum += lds.b.bpl[r];
        st4(wsf + HID + (size_t)b2*512 + rp0 + r, fmaxf(ssum, 0.f));
      }
      __syncthreads();
    }
    gsync(wsu, blk, tid, myGen);

    // ============ Phase 4: logits + softmax/argmax partials; parallel merge ==
    if (blk >= 256) {
      const int blk2 = blk - 256;
      if (blk2 < 250) {
        const int v0 = blk2 * 20;
        const int bb = tid >> 3, ks = tid & 7;       // interleaved K chunks
#pragma unroll
        for (int vi = 0; vi < 20; ++vi) lgv[vi] = 0.f;
        const float* hb = wsf + HID + (size_t)bb*512;
#pragma unroll 1
        for (int half = 0; half < 2; ++half) {       // two K-halves: xr[8] regs
          float4 xr[8];
#pragma unroll
          for (int q = 0; q < 8; ++q) {
            const float* p = hb + ((half*8 + q)*8 + ks)*4;
            float2 a = ld8(p), b2v = ld8(p + 2);
            xr[q] = make_float4(a.x, a.y, b2v.x, b2v.y);
          }
#pragma unroll
          for (int vi = 0; vi < 20; ++vi) {
            float a = 0.f;
#pragma unroll
            for (int q = 0; q < 8; ++q) {
              float4 wv = *(const float4*)(&lds.b.Wc[vi][((half*8 + q)*8 + ks)*4]);
              a += wv.x*xr[q].x + wv.y*xr[q].y + wv.z*xr[q].z + wv.w*xr[q].w;
            }
            lgv[vi] += a;
          }
        }
#pragma unroll
        for (int vi = 0; vi < 20; ++vi) {
          float a = lgv[vi];
          a += __shfl_xor(a, 1); a += __shfl_xor(a, 2); a += __shfl_xor(a, 4);
          lgv[vi] = a + lds.b.bcl[vi];
        }
        float mych = lgv[0]; int ami = 0;
#pragma unroll
        for (int vi = 1; vi < 20; ++vi)
          if (lgv[vi] > mych) { mych = lgv[vi]; ami = vi; }
        float sume = 0.f;
#pragma unroll
        for (int vi = 0; vi < 20; ++vi) sume += expf(lgv[vi] - mych);
        if (ks == 0) {
          st4(wsf + PM + bb*256 + blk2, mych);
          st4(wsf + PSUM + bb*256 + blk2, sume);
          st4i((int*)(wsf + PIDX) + bb*256 + blk2, v0 + ami);
        }
      }
      __syncthreads();   // drain: this block's partials are in L3
      if (tid == 0 && blk2 < 250) add_rlx(&wsu[LCNT], 1u);
      // ---- parallel merge: block 256+b2 owns batch b2 (32 concurrent) ----
      if (blk2 < 32) {
        const int b2 = blk2;
        if (tid == 0) {
          while (ld_rlx(&wsu[LCNT]) < (unsigned)((s + 1) * 250))
            __builtin_amdgcn_s_sleep(2);
        }
        __syncthreads();               // all 250 partials visible
        float mv = -1e30f, sv = 0.f; int iv = 0x7fffffff;
        if (tid < 250) {
          mv = ld4(wsf + PM + b2*256 + tid);
          sv = ld4(wsf + PSUM + b2*256 + tid);
          iv = ld4i((const int*)(wsf + PIDX) + b2*256 + tid);
        }
        scr[tid] = mv; sint[40 + tid] = iv;
        __syncthreads();
        for (int off = 128; off; off >>= 1) {
          if (tid < off) {
            float m2 = scr[tid + off]; int i2 = sint[40 + tid + off];
            if (m2 > scr[tid] || (m2 == scr[tid] && i2 < sint[40 + tid])) {
              scr[tid] = m2; sint[40 + tid] = i2;
            }
          }
          __syncthreads();
        }
        float M = scr[0]; int tok = sint[40];
        __syncthreads();
        scr[tid] = sv * expf(mv - M);
        __syncthreads();
        for (int off = 128; off; off >>= 1) {
          if (tid < off) scr[tid] += scr[tid + off];
          __syncthreads();
        }
        if (tid == 0) st8(wsf + MLS + 2*b2, make_float2(M, logf(scr[0])));
        for (int i = tid; i < 256; i += NT) {
          const float2* er = (const float2*)(Emb + (size_t)tok*512);
          st8(wsf + XH + (size_t)b2*1024 + 2*i, er[i]);
        }
      }
    }
    gsync(wsu, blk, tid, myGen);
  }

  // ---------------- epilogue: step 63's log-softmax from registers ----------
  if (blk >= 256) {
    const int blk2 = blk - 256;
    if (blk2 < 250) {
      const int v0 = blk2 * 20, bb = tid >> 3, ks = tid & 7;
      if (ks == 0) {
        float2 ml = ld8(wsf + MLS + 2*bb);
        float sub = ml.x + ml.y;
#pragma unroll
        for (int vi = 0; vi < 20; ++vi)
          out[(size_t)63*160000 + (size_t)bb*5000 + v0 + vi] = lgv[vi] - sub;
      }
    }
  }
}

extern "C" void kernel_launch(void* const* d_in, const int* in_sizes, int n_in,
                              void* d_out, int out_size, void* d_ws, size_t ws_size,
                              hipStream_t stream) {
  (void)in_sizes; (void)n_in; (void)out_size; (void)ws_size;
  const float* LF  = (const float*)d_in[0];
  const float* Emb = (const float*)d_in[1];
  const float* Wih = (const float*)d_in[2];
  const float* Whh = (const float*)d_in[3];
  const float* bih = (const float*)d_in[4];
  const float* bhh = (const float*)d_in[5];
  const float* Wp  = (const float*)d_in[6];
  const float* bp  = (const float*)d_in[7];
  const float* Wc  = (const float*)d_in[8];
  const float* bc  = (const float*)d_in[9];
  float* out = (float*)d_out;
  unsigned* wsu = (unsigned*)d_ws;
  float* wsf = (float*)d_ws + WSU;

  speller_init<<<32, NT, 0, stream>>>(LF, Emb, wsf, wsu);
  speller_main<<<NB, NT, 0, stream>>>(LF, Emb, Wih, Whh, bih, bhh, Wp, bp, Wc, bc,
                                      out, wsu, wsf);
}

// Round 5
// 6665.302 us; speedup vs baseline: 1.8707x; 1.0115x over previous
//
#include <hip/hip_runtime.h>
#include <math.h>
#include <stdint.h>

// ---------------------------------------------------------------------------
// Speller decoder, persistent kernel, 512 blocks x 256 threads.
// R8: phase-1 software pipelining. The gate GEMM's K-range splits by
// dependency: emb (K<512) needs step s's token (P4); ctx+h (K>=512) are
// final right after P2/P1 of step s. Gate blocks now compute the ctx+h
// partial gates for step s+1 DURING step s's P3 window (previously idle),
// carrying the partial acc in registers across barriers; W1 only adds the
// emb part + reduce + LSTM. Phase 1 re-decomposed 16 slots x 2 batches
// (acc[8][2]=16 VGPR carried, c_reg[2][2]) to fit the register budget.
// R7/R6: LF register-resident (128 VGPR/thread, loaded once; phase-2 does
// zero LF memory traffic; keep/send reduce-scatter). R5: parallel per-batch
// phase-4 merge. R3: relaxed AGENT-scope atomics through L3, monotonic
// counter barriers.
// ---------------------------------------------------------------------------

#define NB 512
#define NT 256

constexpr int Tv = 1024, Vv = 5000, STEPS = 64;

// ---- u32 counter region (all monotonic, zeroed by init kernel) ----
constexpr int MCNT = 0;               // master barrier counter
constexpr int GEN  = 16;              // barrier generation
constexpr int GCNT = 64;              // 32 group counters, stride 16
constexpr int GFLG = 1024;            // 32 group release flags, stride 32
constexpr int ACNT = 2048;            // 32 attn-merge counters, stride 16
constexpr int LCNT = 2560;            // single logits-arrival counter
constexpr int WSU  = 4096;

// ---- float region offsets (wsf = (float*)ws + WSU) ----
constexpr int XH   = 0;                    // [32][1024] = emb(512) | ctx(512)
constexpr int HB   = XH + 32*1024;         // [2][32][512] h double-buffer
constexpr int HID  = HB + 2*32*512;        // [32][512]
constexpr int PART = HID + 32*512;         // [32][4][16][130] attn partials
constexpr int E3   = PART + 32*4*16*130;   // [32][1024] head-3 energies
constexpr int PM   = E3 + 32*1024;         // [32][256] chunk max
constexpr int PSUM = PM + 32*256;          // [32][256] chunk sumexp
constexpr int PIDX = PSUM + 32*256;        // [32][256] chunk argmax (int)
constexpr int MLS  = PIDX + 32*256;        // [32][2] (max, lse)

__device__ __forceinline__ float sigm(float x) { return 1.f / (1.f + expf(-x)); }

// ---- coherent (L3, sc0 sc1) access helpers: relaxed agent atomics ----
__device__ __forceinline__ float ld4(const float* p) {
  return __hip_atomic_load(const_cast<float*>(p), __ATOMIC_RELAXED, __HIP_MEMORY_SCOPE_AGENT);
}
__device__ __forceinline__ void st4(float* p, float v) {
  __hip_atomic_store(p, v, __ATOMIC_RELAXED, __HIP_MEMORY_SCOPE_AGENT);
}
__device__ __forceinline__ float2 ld8(const float* p) {
  unsigned long long u = __hip_atomic_load(
      reinterpret_cast<unsigned long long*>(const_cast<float*>(p)),
      __ATOMIC_RELAXED, __HIP_MEMORY_SCOPE_AGENT);
  union { unsigned long long u; float2 f; } c; c.u = u; return c.f;
}
__device__ __forceinline__ void st8(float* p, float2 v) {
  union { float2 f; unsigned long long u; } c; c.f = v;
  __hip_atomic_store(reinterpret_cast<unsigned long long*>(p), c.u,
                     __ATOMIC_RELAXED, __HIP_MEMORY_SCOPE_AGENT);
}
__device__ __forceinline__ int ld4i(const int* p) {
  return (int)__hip_atomic_load(reinterpret_cast<unsigned*>(const_cast<int*>(p)),
                                __ATOMIC_RELAXED, __HIP_MEMORY_SCOPE_AGENT);
}
__device__ __forceinline__ void st4i(int* p, int v) {
  __hip_atomic_store(reinterpret_cast<unsigned*>(p), (unsigned)v,
                     __ATOMIC_RELAXED, __HIP_MEMORY_SCOPE_AGENT);
}
__device__ __forceinline__ unsigned ld_rlx(unsigned* p) {
  return __hip_atomic_load(p, __ATOMIC_RELAXED, __HIP_MEMORY_SCOPE_AGENT);
}
__device__ __forceinline__ void st_rlx(unsigned* p, unsigned v) {
  __hip_atomic_store(p, v, __ATOMIC_RELAXED, __HIP_MEMORY_SCOPE_AGENT);
}
__device__ __forceinline__ unsigned add_rlx(unsigned* p, unsigned v) {
  return __hip_atomic_fetch_add(p, v, __ATOMIC_RELAXED, __HIP_MEMORY_SCOPE_AGENT);
}

// Device barrier: NO cache ops. __syncthreads drains vmcnt (sc1 stores are
// then in L3 = globally visible); counters/flags are relaxed sc1 atomics.
__device__ __forceinline__ void gsync(unsigned* wsu, int blk, int tid, unsigned& myGen) {
  __syncthreads();
  if (tid == 0) {
    const unsigned target = ++myGen;
    const int grp = blk >> 4;
    unsigned o = add_rlx(&wsu[GCNT + grp*16], 1u);
    if (o == target*16u - 1u) {
      unsigned o2 = add_rlx(&wsu[MCNT], 1u);
      if (o2 == target*32u - 1u) st_rlx(&wsu[GEN], target);
    }
    if ((blk & 15) == 0) {
      while (ld_rlx(&wsu[GEN]) != target) __builtin_amdgcn_s_sleep(2);
      st_rlx(&wsu[GFLG + grp*32], target);
    } else {
      while (ld_rlx(&wsu[GFLG + grp*32]) != target) __builtin_amdgcn_s_sleep(2);
    }
  }
  __syncthreads();
}

__global__ void speller_init(const float* __restrict__ LF, const float* __restrict__ Emb,
                             float* __restrict__ wsf, unsigned* __restrict__ wsu) {
  int b = blockIdx.x;
  for (int i = threadIdx.x; i < 512; i += NT) {
    st4(wsf + XH + b*1024 + i,       Emb[i]);                    // emb row 0
    st4(wsf + XH + b*1024 + 512 + i, LF[(size_t)b*Tv*512 + i]);  // ctx0 = LF[b,0,:]
    st4(wsf + HB + b*512 + i,        0.f);                       // h0 (buffer 0)
  }
  if (b == 0) for (int i = threadIdx.x; i < WSU; i += NT) st_rlx(wsu + i, 0u);
}

struct LdsA { float Wg[8][1536]; float gb[8]; };   // gate rows: i,i,f,f,g,g,o,o of units 2j,2j+1
struct LdsB { float Wc[20][512]; float Wp[2][1024]; float bcl[20]; float bpl[2]; };
union  LdsU { LdsA a; LdsB b; };

// A-part of the gate GEMM for one step: K in [512,1536) = ctx | h.
// acc[8][2] accumulates rows (gate,unit) x 2 batches for lane (slot,ks).
__device__ __forceinline__ void gate_accum_A(float acc[8][2], const float* __restrict__ wsf,
                                             const float (&Wg)[8][1536],
                                             int ks, int b0, int hbuf) {
#pragma unroll 2
  for (int q = 0; q < 8; ++q) {              // ctx: k in [512,1024)
    const int k4 = 512 + (q*16 + ks)*4;
    float2 xa[2], xb[2];
#pragma unroll
    for (int i = 0; i < 2; ++i) {
      const float* p = wsf + XH + (size_t)(b0+i)*1024 + k4;
      xa[i] = ld8(p); xb[i] = ld8(p + 2);
    }
#pragma unroll
    for (int r = 0; r < 8; ++r) {
      float4 wv = *(const float4*)(&Wg[r][k4]);
#pragma unroll
      for (int i = 0; i < 2; ++i)
        acc[r][i] += wv.x*xa[i].x + wv.y*xa[i].y + wv.z*xb[i].x + wv.w*xb[i].y;
    }
  }
#pragma unroll 2
  for (int q = 0; q < 8; ++q) {              // h: k in [1024,1536)
    const int k4 = (q*16 + ks)*4;
    float2 xa[2], xb[2];
#pragma unroll
    for (int i = 0; i < 2; ++i) {
      const float* p = wsf + HB + hbuf*16384 + (size_t)(b0+i)*512 + k4;
      xa[i] = ld8(p); xb[i] = ld8(p + 2);
    }
#pragma unroll
    for (int r = 0; r < 8; ++r) {
      float4 wv = *(const float4*)(&Wg[r][1024 + k4]);
#pragma unroll
      for (int i = 0; i < 2; ++i)
        acc[r][i] += wv.x*xa[i].x + wv.y*xa[i].y + wv.z*xb[i].x + wv.w*xb[i].y;
    }
  }
}

__launch_bounds__(NT, 2)
__global__ void speller_main(const float* __restrict__ LF, const float* __restrict__ Emb,
                             const float* __restrict__ Wih, const float* __restrict__ Whh,
                             const float* __restrict__ bih, const float* __restrict__ bhh,
                             const float* __restrict__ Wp,  const float* __restrict__ bp,
                             const float* __restrict__ Wc,  const float* __restrict__ bc,
                             float* __restrict__ out, unsigned* __restrict__ wsu,
                             float* __restrict__ wsf) {
  const int blk = blockIdx.x, tid = threadIdx.x;
  unsigned myGen = 0;
  __shared__ LdsU lds;
  __shared__ float scr[784];
  __shared__ int  sint[300];

  const int ab = blk >> 4, atc = blk & 15;         // attention chunk identity
  const int aw = tid >> 6, aln = tid & 63;         // head / t-row lane

  // ---- persistent LF slice: LF[ab, atc*64+aln, aw*128 .. +127] ----
  float4 lfr[32];
  {
    const float4* src = (const float4*)(LF +
        (((size_t)ab*Tv + atc*64 + aln)*512 + aw*128));
#pragma unroll
    for (int q = 0; q < 32; ++q) lfr[q] = src[q];
  }

  // ---------------- one-time LDS weight preload (plain cached loads) -------
  if (blk < 256) {
    const int u0 = blk * 2;
    for (int idx = tid; idx < 8*1536; idx += NT) {
      int r = idx / 1536, k = idx - r*1536;
      int g = r >> 1, uu = r & 1;
      int row = g*512 + u0 + uu;
      lds.a.Wg[r][k] = (k < 1024) ? Wih[(size_t)row*1024 + k]
                                  : Whh[(size_t)row*512 + (k-1024)];
    }
    if (tid < 8) {
      int g = tid >> 1, uu = tid & 1, row = g*512 + u0 + uu;
      lds.a.gb[tid] = bih[row] + bhh[row];
    }
  } else {
    const int blk2 = blk - 256, v0 = blk2*20, rp0 = blk2*2;
    if (v0 < Vv) {
      for (int idx = tid; idx < 20*512; idx += NT) {
        int vi = idx >> 9, k = idx & 511;
        lds.b.Wc[vi][k] = Wc[(size_t)(v0+vi)*512 + k];
      }
      if (tid < 20) lds.b.bcl[tid] = bc[v0+tid];
    }
    for (int idx = tid; idx < 2048; idx += NT) {
      int r = idx >> 10, k = idx & 1023;
      lds.b.Wp[r][k] = Wp[(size_t)(rp0+r)*1024 + k];
    }
    if (tid < 2) lds.b.bpl[tid] = bp[rp0+tid];
  }
  __syncthreads();

  float acc[8][2];                   // carried partial gates (A-part pipeline)
  float c_reg[2][2];                 // cell state, lives in registers all run
#pragma unroll
  for (int uu = 0; uu < 2; ++uu)
#pragma unroll
    for (int i = 0; i < 2; ++i) c_reg[uu][i] = 0.f;
  float lgv[20];                     // logits carried phase4 -> next phase1

  // ---- prologue: A-part (ctx0|h0) of step 0's gates ----
  if (blk < 256) {
    const int ks = tid & 15, b0 = (tid >> 4) * 2;
#pragma unroll
    for (int r = 0; r < 8; ++r)
#pragma unroll
      for (int i = 0; i < 2; ++i) acc[r][i] = 0.f;
    gate_accum_A(acc, wsf, lds.a.Wg, ks, b0, 0);
  }

#pragma unroll 1
  for (int s = 0; s < STEPS; ++s) {
    const int wbuf = (s + 1) & 1;

    // ===== W1: emb-part + LSTM finish (blk<256) | out-write (>=256) ========
    if (blk < 256) {
      const int u0 = blk * 2;
      const int ks = tid & 15, b0 = (tid >> 4) * 2;
#pragma unroll 2
      for (int q = 0; q < 8; ++q) {          // emb: k in [0,512)
        const int k4 = (q*16 + ks)*4;
        float2 xa[2], xb[2];
#pragma unroll
        for (int i = 0; i < 2; ++i) {
          const float* p = wsf + XH + (size_t)(b0+i)*1024 + k4;
          xa[i] = ld8(p); xb[i] = ld8(p + 2);
        }
#pragma unroll
        for (int r = 0; r < 8; ++r) {
          float4 wv = *(const float4*)(&lds.a.Wg[r][k4]);
#pragma unroll
          for (int i = 0; i < 2; ++i)
            acc[r][i] += wv.x*xa[i].x + wv.y*xa[i].y + wv.z*xb[i].x + wv.w*xb[i].y;
        }
      }
#pragma unroll
      for (int r = 0; r < 8; ++r)
#pragma unroll
        for (int i = 0; i < 2; ++i) {
          float v = acc[r][i];
          v += __shfl_xor(v, 8); v += __shfl_xor(v, 4);
          v += __shfl_xor(v, 2); v += __shfl_xor(v, 1);
          acc[r][i] = v + lds.a.gb[r];
        }
      // fused LSTM pointwise (rows: i=uu, f=2+uu, g=4+uu, o=6+uu)
      float hnew[2][2];
#pragma unroll
      for (int uu = 0; uu < 2; ++uu)
#pragma unroll
        for (int i = 0; i < 2; ++i) {
          float cn = sigm(acc[2+uu][i]) * c_reg[uu][i]
                   + sigm(acc[uu][i]) * tanhf(acc[4+uu][i]);
          c_reg[uu][i] = cn;
          hnew[uu][i] = sigm(acc[6+uu][i]) * tanhf(cn);
        }
      if (ks == 0) {
#pragma unroll
        for (int i = 0; i < 2; ++i)
          st8(wsf + HB + wbuf*16384 + (size_t)(b0+i)*512 + u0,
              make_float2(hnew[0][i], hnew[1][i]));
      }
    } else if (s > 0) {
      const int blk2 = blk - 256;
      if (blk2 < 250) {
        const int v0 = blk2 * 20, bb = tid >> 3, ks = tid & 7;
        if (ks == 0) {
          float2 ml = ld8(wsf + MLS + 2*bb);
          float sub = ml.x + ml.y;
#pragma unroll
          for (int vi = 0; vi < 20; ++vi)
            out[(size_t)(s-1)*160000 + (size_t)bb*5000 + v0 + vi] = lgv[vi] - sub;
        }
      }
    }
    gsync(wsu, blk, tid, myGen);

    // ============ W2: attention from register-resident LF ===================
    {
      float* hs = scr;  // [512] decoder state
      {
        float2 hv = ld8(wsf + HB + wbuf*16384 + (size_t)ab*512 + tid*2);
        hs[tid*2] = hv.x; hs[tid*2+1] = hv.y;
      }
      __syncthreads();
      float e = 0.f;
      {
        const float4* hp = (const float4*)(hs + aw*128);
#pragma unroll
        for (int q = 0; q < 32; ++q) {
          float4 f = lfr[q], hh = hp[q];
          e += f.x*hh.x + f.y*hh.y + f.z*hh.z + f.w*hh.w;
        }
      }
      float m = e;
#pragma unroll
      for (int off = 32; off; off >>= 1) m = fmaxf(m, __shfl_xor(m, off));
      float p = expf(e - m);
      float l = p;
#pragma unroll
      for (int off = 32; off; off >>= 1) l += __shfl_xor(l, off);
      if (aw == 3) st4(wsf + E3 + (size_t)ab*1024 + atc*64 + aln, e);
      float* pr = wsf + PART + (size_t)((ab*4 + aw)*16 + atc)*130;
#pragma unroll
      for (int ch = 0; ch < 2; ++ch) {             // fully unrolled: lfr idx static
        float c[64];
#pragma unroll
        for (int q = 0; q < 16; ++q) {
          float4 f = lfr[ch*16 + q];
          c[4*q+0] = p*f.x; c[4*q+1] = p*f.y; c[4*q+2] = p*f.z; c[4*q+3] = p*f.w;
        }
#pragma unroll
        for (int o = 32; o >= 1; o >>= 1) {
#pragma unroll
          for (int j = 0; j < 32; ++j) {
            if (j < o) {
              float keep = (aln & o) ? c[j + o] : c[j];
              float send = (aln & o) ? c[j] : c[j + o];
              c[j] = keep + __shfl_xor(send, o);
            }
          }
        }
        st4(pr + 2 + ch*64 + aln, c[0]);
      }
      if (aln == 0) st8(pr, make_float2(m, l));
      __syncthreads();   // drains vmcnt: all this block's partials are in L3
      if (tid == 0) {
        unsigned old = add_rlx(&wsu[ACNT + ab*16], 1u);
        sint[0] = (old == (unsigned)(s*16 + 15));
      }
      __syncthreads();
      if (sint[0]) {                       // last arriver merges the 16 chunks
        const int w2 = tid >> 6, ln2 = tid & 63;
        const float* pb = wsf + PART + (size_t)(ab*4 + w2)*16*130;
        float M = -1e30f;
        float mv[16], lv[16];
#pragma unroll
        for (int i = 0; i < 16; ++i) { float2 t = ld8(pb + i*130); mv[i] = t.x; lv[i] = t.y; M = fmaxf(M, t.x); }
        float L = 0.f;
        float sc[16];
#pragma unroll
        for (int i = 0; i < 16; ++i) { sc[i] = expf(mv[i] - M); L += lv[i] * sc[i]; }
        float cc0 = 0.f, cc1 = 0.f;
#pragma unroll
        for (int i = 0; i < 16; ++i) {
          float2 cx = ld8(pb + i*130 + 2 + 2*ln2);
          cc0 += sc[i]*cx.x; cc1 += sc[i]*cx.y;
        }
        float invL = 1.f / L;
        st8(wsf + XH + (size_t)ab*1024 + 512 + w2*128 + 2*ln2,
            make_float2(cc0*invL, cc1*invL));
        if (ln2 == 0) { scr[768 + w2*2] = M; scr[769 + w2*2] = L; }
        __syncthreads();
        float M3 = scr[768 + 6], iL3 = 1.f / scr[768 + 7];
        for (int i = tid; i < 1024; i += NT)
          out[(size_t)10240000 + ((size_t)(s*32 + ab))*1024 + i] =
              expf(ld4(wsf + E3 + (size_t)ab*1024 + i) - M3) * iL3;
      }
    }
    gsync(wsu, blk, tid, myGen);

    // ===== W3: MLP (blk>=256) || next-step A-part gates (blk<256) ==========
    if (blk >= 256) {
      const int blk2 = blk - 256, rp0 = blk2*2;
      const int bb = tid & 31, ks = tid >> 5;        // 8 K-windows of 128
      const float* xr = (ks < 4) ? (wsf + HB + wbuf*16384 + (size_t)bb*512 + ks*128)
                                 : (wsf + XH + (size_t)bb*1024 + (ks-4)*128 + 512);
      const int kb = ks * 128;
      const float4* w0 = (const float4*)(&lds.b.Wp[0][kb]);
      const float4* w1 = (const float4*)(&lds.b.Wp[1][kb]);
      float a0 = 0.f, a1 = 0.f;
#pragma unroll 8
      for (int q = 0; q < 32; ++q) {
        float2 xva = ld8(xr + q*4), xvb = ld8(xr + q*4 + 2);
        float4 wv0 = w0[q], wv1 = w1[q];
        a0 += wv0.x*xva.x + wv0.y*xva.y + wv0.z*xvb.x + wv0.w*xvb.y;
        a1 += wv1.x*xva.x + wv1.y*xva.y + wv1.z*xvb.x + wv1.w*xvb.y;
      }
      scr[ks*32 + bb] = a0; scr[256 + ks*32 + bb] = a1;
      __syncthreads();
      if (tid < 64) {
        int r = tid >> 5, b2 = tid & 31;
        float ssum = 0.f;
#pragma unroll
        for (int j = 0; j < 8; ++j) ssum += scr[r*256 + j*32 + b2];
        ssum += lds.b.bpl[r];
        st4(wsf + HID + (size_t)b2*512 + rp0 + r, fmaxf(ssum, 0.f));
      }
      __syncthreads();
    } else if (s < 63) {
      // pipeline: A-part (ctx|h) of step s+1's gates, overlapped with P3
      const int ks = tid & 15, b0 = (tid >> 4) * 2;
#pragma unroll
      for (int r = 0; r < 8; ++r)
#pragma unroll
        for (int i = 0; i < 2; ++i) acc[r][i] = 0.f;
      gate_accum_A(acc, wsf, lds.a.Wg, ks, b0, wbuf);
    }
    gsync(wsu, blk, tid, myGen);

    // ============ W4: logits + softmax/argmax partials; parallel merge ======
    if (blk >= 256) {
      const int blk2 = blk - 256;
      if (blk2 < 250) {
        const int v0 = blk2 * 20;
        const int bb = tid >> 3, ks = tid & 7;       // interleaved K chunks
#pragma unroll
        for (int vi = 0; vi < 20; ++vi) lgv[vi] = 0.f;
        const float* hb = wsf + HID + (size_t)bb*512;
#pragma unroll 1
        for (int half = 0; half < 2; ++half) {       // two K-halves: xr[8] regs
          float4 xr[8];
#pragma unroll
          for (int q = 0; q < 8; ++q) {
            const float* p = hb + ((half*8 + q)*8 + ks)*4;
            float2 a = ld8(p), b2v = ld8(p + 2);
            xr[q] = make_float4(a.x, a.y, b2v.x, b2v.y);
          }
#pragma unroll
          for (int vi = 0; vi < 20; ++vi) {
            float a = 0.f;
#pragma unroll
            for (int q = 0; q < 8; ++q) {
              float4 wv = *(const float4*)(&lds.b.Wc[vi][((half*8 + q)*8 + ks)*4]);
              a += wv.x*xr[q].x + wv.y*xr[q].y + wv.z*xr[q].z + wv.w*xr[q].w;
            }
            lgv[vi] += a;
          }
        }
#pragma unroll
        for (int vi = 0; vi < 20; ++vi) {
          float a = lgv[vi];
          a += __shfl_xor(a, 1); a += __shfl_xor(a, 2); a += __shfl_xor(a, 4);
          lgv[vi] = a + lds.b.bcl[vi];
        }
        float mych = lgv[0]; int ami = 0;
#pragma unroll
        for (int vi = 1; vi < 20; ++vi)
          if (lgv[vi] > mych) { mych = lgv[vi]; ami = vi; }
        float sume = 0.f;
#pragma unroll
        for (int vi = 0; vi < 20; ++vi) sume += expf(lgv[vi] - mych);
        if (ks == 0) {
          st4(wsf + PM + bb*256 + blk2, mych);
          st4(wsf + PSUM + bb*256 + blk2, sume);
          st4i((int*)(wsf + PIDX) + bb*256 + blk2, v0 + ami);
        }
      }
      __syncthreads();   // drain: this block's partials are in L3
      if (tid == 0 && blk2 < 250) add_rlx(&wsu[LCNT], 1u);
      // ---- parallel merge: block 256+b2 owns batch b2 (32 concurrent) ----
      if (blk2 < 32) {
        const int b2 = blk2;
        if (tid == 0) {
          while (ld_rlx(&wsu[LCNT]) < (unsigned)((s + 1) * 250))
            __builtin_amdgcn_s_sleep(2);
        }
        __syncthreads();               // all 250 partials visible
        float mv = -1e30f, sv = 0.f; int iv = 0x7fffffff;
        if (tid < 250) {
          mv = ld4(wsf + PM + b2*256 + tid);
          sv = ld4(wsf + PSUM + b2*256 + tid);
          iv = ld4i((const int*)(wsf + PIDX) + b2*256 + tid);
        }
        scr[tid] = mv; sint[40 + tid] = iv;
        __syncthreads();
        for (int off = 128; off; off >>= 1) {
          if (tid < off) {
            float m2 = scr[tid + off]; int i2 = sint[40 + tid + off];
            if (m2 > scr[tid] || (m2 == scr[tid] && i2 < sint[40 + tid])) {
              scr[tid] = m2; sint[40 + tid] = i2;
            }
          }
          __syncthreads();
        }
        float M = scr[0]; int tok = sint[40];
        __syncthreads();
        scr[tid] = sv * expf(mv - M);
        __syncthreads();
        for (int off = 128; off; off >>= 1) {
          if (tid < off) scr[tid] += scr[tid + off];
          __syncthreads();
        }
        if (tid == 0) st8(wsf + MLS + 2*b2, make_float2(M, logf(scr[0])));
        for (int i = tid; i < 256; i += NT) {
          const float2* er = (const float2*)(Emb + (size_t)tok*512);
          st8(wsf + XH + (size_t)b2*1024 + 2*i, er[i]);
        }
      }
    }
    gsync(wsu, blk, tid, myGen);
  }

  // ---------------- epilogue: step 63's log-softmax from registers ----------
  if (blk >= 256) {
    const int blk2 = blk - 256;
    if (blk2 < 250) {
      const int v0 = blk2 * 20, bb = tid >> 3, ks = tid & 7;
      if (ks == 0) {
        float2 ml = ld8(wsf + MLS + 2*bb);
        float sub = ml.x + ml.y;
#pragma unroll
        for (int vi = 0; vi < 20; ++vi)
          out[(size_t)63*160000 + (size_t)bb*5000 + v0 + vi] = lgv[vi] - sub;
      }
    }
  }
}

extern "C" void kernel_launch(void* const* d_in, const int* in_sizes, int n_in,
                              void* d_out, int out_size, void* d_ws, size_t ws_size,
                              hipStream_t stream) {
  (void)in_sizes; (void)n_in; (void)out_size; (void)ws_size;
  const float* LF  = (const float*)d_in[0];
  const float* Emb = (const float*)d_in[1];
  const float* Wih = (const float*)d_in[2];
  const float* Whh = (const float*)d_in[3];
  const float* bih = (const float*)d_in[4];
  const float* bhh = (const float*)d_in[5];
  const float* Wp  = (const float*)d_in[6];
  const float* bp  = (const float*)d_in[7];
  const float* Wc  = (const float*)d_in[8];
  const float* bc  = (const float*)d_in[9];
  float* out = (float*)d_out;
  unsigned* wsu = (unsigned*)d_ws;
  float* wsf = (float*)d_ws + WSU;

  speller_init<<<32, NT, 0, stream>>>(LF, Emb, wsf, wsu);
  speller_main<<<NB, NT, 0, stream>>>(LF, Emb, Wih, Whh, bih, bhh, Wp, bp, Wc, bc,
                                      out, wsu, wsf);
}